// Round 6
// baseline (78044.678 us; speedup 1.0000x reference)
//
#include <hip/hip_runtime.h>
#include <hip/hip_bf16.h>

#define VOCAB  32000
#define DIM    1024
#define NLAYER 4
#define NB     8
#define SEQ    512

#define SCAN_BLOCKS  256
#define SCAN_THREADS 512   // 8 waves = 4 rows x 2 half-waves; 2048 waves total

typedef __attribute__((ext_vector_type(8))) short          bf16x8;
typedef __attribute__((ext_vector_type(4))) float          f32x4;
typedef __attribute__((ext_vector_type(8))) unsigned short u16x8;

__device__ __forceinline__ float fma4(float4 a, float4 b, float acc) {
    acc = fmaf(a.x, b.x, acc);
    acc = fmaf(a.y, b.y, acc);
    acc = fmaf(a.z, b.z, acc);
    acc = fmaf(a.w, b.w, acc);
    return acc;
}

__device__ __forceinline__ void bfly(float& v) {
    #pragma unroll
    for (int off = 32; off > 0; off >>= 1) v += __shfl_xor(v, off);
}

__device__ __forceinline__ u16x8 cvt8_bf16(const float* p) {
    float4 f0 = *(const float4*)p;
    float4 f1 = *(const float4*)(p + 4);
    union { __hip_bfloat16 h[8]; u16x8 v; } u;
    u.h[0] = __float2bfloat16(f0.x); u.h[1] = __float2bfloat16(f0.y);
    u.h[2] = __float2bfloat16(f0.z); u.h[3] = __float2bfloat16(f0.w);
    u.h[4] = __float2bfloat16(f1.x); u.h[5] = __float2bfloat16(f1.y);
    u.h[6] = __float2bfloat16(f1.z); u.h[7] = __float2bfloat16(f1.w);
    return u.v;
}

// ---------------------------------------------------------------------------
__global__ void bar_init_kernel(unsigned* __restrict__ bar) {
    bar[threadIdx.x] = 0u;   // 1024 words
}

// ---------------------------------------------------------------------------
// Two-level monotonic grid barrier, AGENT scope (cross-XCD safe; proven in
// rounds 3-5). Timeout -> dead flag -> 1e8 sentinel in ysf.
// ---------------------------------------------------------------------------
__device__ __forceinline__ void gbar(unsigned* bar, unsigned& ep, bool& dead) {
    __syncthreads();
    if (threadIdx.x == 0 && !dead) {
        unsigned* root = bar;
        unsigned* leaf = bar + 32 + 32 * (blockIdx.x & 7);
        unsigned old = __hip_atomic_fetch_add(leaf, 1u, __ATOMIC_ACQ_REL,
                                              __HIP_MEMORY_SCOPE_AGENT);
        if (old == ep * (SCAN_BLOCKS / 8) - 1)
            __hip_atomic_fetch_add(root, 1u, __ATOMIC_ACQ_REL,
                                   __HIP_MEMORY_SCOPE_AGENT);
        unsigned guard = 0;
        while (__hip_atomic_load(root, __ATOMIC_RELAXED,
                                 __HIP_MEMORY_SCOPE_AGENT) < ep * 8u) {
            __builtin_amdgcn_s_sleep(8);
            if (++guard > (1u << 17)) { dead = true; break; }
        }
        (void)__hip_atomic_load(root, __ATOMIC_ACQUIRE,
                                __HIP_MEMORY_SCOPE_AGENT);
    }
    __syncthreads();
    ep++;
}

// ---------------------------------------------------------------------------
// Persistent-weight GRU scan, row-split across wave pairs.
// Block bk owns rows j = bk*4 + rw, rw=0..3. Wave wv: rw = wv>>1, hf = wv&1.
//   hf=0 wave: x-half  (k in [0,1024))  of gate-z, gate-r, cand rows -> 192 VGPR
//   hf=1 wave: h-half  (k in [1024,2048)) of gate-z, gate-r, cand rows -> 192 VGPR
// Per (t,ly): stage xin->lx, h_old->lh; phase A partial dots (hf0 over lx:
// z,r,c; hf1 over lh: z,r) -> butterfly reduce -> pp LDS; hf1 lanes 0-7
// combine gates (sigmoid), keep z in zz LDS, publish r to global rbuf; gbar;
// stage rh=r*h -> lx; hf1 computes candB dot + tanh + state update; gbar.
// ---------------------------------------------------------------------------
__global__ void __launch_bounds__(SCAN_THREADS, 2) gru_scan(
    const int*   __restrict__ ids,     // [NB][SEQ]
    const float* __restrict__ embW,    // [VOCAB][DIM]
    const float* __restrict__ hstart,  // [NLAYER][DIM]
    const float* __restrict__ gW,      // [NLAYER][2*DIM][2*DIM]
    const float* __restrict__ gB,      // [NLAYER][2*DIM]
    const float* __restrict__ cW,      // [NLAYER][DIM][2*DIM]
    const float* __restrict__ cB,      // [NLAYER][DIM]
    float* __restrict__ hbuf,          // [2][NLAYER][NB][DIM]
    float* __restrict__ rbuf,          // [NB][DIM]
    float* __restrict__ ysf,           // [NB][SEQ][DIM] fp32
    unsigned* __restrict__ bar)
{
    __shared__ float lx[NB][DIM];      // 32KB: xin (phase A) / rh (phase B)
    __shared__ float lh[NB][DIM];      // 32KB: old h
    __shared__ float pp[4][5][NB];     // partials: zx,rx,cx,zh,rh
    __shared__ float zz[4][NB];        // combined z gate

    const int tid  = threadIdx.x;
    const int lane = tid & 63;
    const int wv   = tid >> 6;         // 0..7
    const int rw   = wv >> 1;          // row within block 0..3
    const int hf   = wv & 1;           // 0: x-half, 1: h-half
    const int j    = blockIdx.x * 4 + rw;

    // ---- persistent weight preload: 48 float4 = 192 VGPRs/lane ----
    // W[ly][0..3]=z-row half, [4..7]=r-row half, [8..11]=c-row half
    float4 W[NLAYER][12];
    {
        const int kb = hf * 1024;
        #pragma unroll
        for (int ly = 0; ly < NLAYER; ++ly) {
            const float* wz = gW + ((size_t)ly * 2048 + j) * 2048 + kb;
            const float* wr = gW + ((size_t)ly * 2048 + 1024 + j) * 2048 + kb;
            const float* wc = cW + ((size_t)ly * 1024 + j) * 2048 + kb;
            #pragma unroll
            for (int it = 0; it < 4; ++it) {
                const int k0 = it * 256 + lane * 4;
                W[ly][it]     = *(const float4*)(wz + k0);
                W[ly][4 + it] = *(const float4*)(wr + k0);
                W[ly][8 + it] = *(const float4*)(wc + k0);
            }
        }
    }

    unsigned ep = 1;
    bool dead = false;

    // init h parity-0 buffer: hbuf[0][layer][b][d] = hstart[layer][d]
    {
        int g = blockIdx.x * SCAN_THREADS + tid;
        if (g < NLAYER * NB * DIM)
            hbuf[g] = hstart[((g >> 13) << 10) | (g & (DIM - 1))];
    }
    gbar(bar, ep, dead);

    for (int t = 0; t < SEQ; ++t) {
        const float* hR  = hbuf + (t & 1)       * (NLAYER * NB * DIM);
        float*       hWp = hbuf + ((t & 1) ^ 1) * (NLAYER * NB * DIM);

        #pragma unroll
        for (int ly = 0; ly < NLAYER; ++ly) {
            // ---- stage xin -> lx and h_old -> lh (4 float4 per thread each) ----
            if (ly == 0) {
                #pragma unroll
                for (int q = 0; q < 4; ++q) {
                    int e = q * SCAN_THREADS + tid;          // 0..2047
                    int b = e >> 8;
                    int row = ids[b * SEQ + t];
                    ((float4*)&lx[0][0])[e] =
                        ((const float4*)(embW + (size_t)row * DIM))[e & 255];
                }
            } else {
                const float* src = hWp + (ly - 1) * NB * DIM;
                #pragma unroll
                for (int q = 0; q < 4; ++q) {
                    int e = q * SCAN_THREADS + tid;
                    ((float4*)&lx[0][0])[e] = ((const float4*)src)[e];
                }
            }
            {
                const float* src = hR + ly * NB * DIM;
                #pragma unroll
                for (int q = 0; q < 4; ++q) {
                    int e = q * SCAN_THREADS + tid;
                    ((float4*)&lh[0][0])[e] = ((const float4*)src)[e];
                }
            }
            __syncthreads();

            // ---- Phase A: partial dots over this wave's k-half ----
            float a0[NB] = {0,0,0,0,0,0,0,0};   // z partial
            float a1[NB] = {0,0,0,0,0,0,0,0};   // r partial
            float a2[NB] = {0,0,0,0,0,0,0,0};   // c partial (hf0) / candB (hf1, phase B)

            if (hf == 0) {
                #pragma unroll
                for (int it = 0; it < 4; ++it) {
                    const int k0 = it * 256 + lane * 4;
                    #pragma unroll
                    for (int b = 0; b < NB; ++b) {
                        const float4 v = *(const float4*)&lx[b][k0];
                        a0[b] = fma4(W[ly][it],     v, a0[b]);
                        a1[b] = fma4(W[ly][4 + it], v, a1[b]);
                        a2[b] = fma4(W[ly][8 + it], v, a2[b]);
                    }
                }
                #pragma unroll
                for (int b = 0; b < NB; ++b) { bfly(a0[b]); bfly(a1[b]); bfly(a2[b]); }
                if (lane == 0) {
                    #pragma unroll
                    for (int b = 0; b < NB; ++b) {
                        pp[rw][0][b] = a0[b];
                        pp[rw][1][b] = a1[b];
                        pp[rw][2][b] = a2[b];
                    }
                }
            } else {
                #pragma unroll
                for (int it = 0; it < 4; ++it) {
                    const int k0 = it * 256 + lane * 4;
                    #pragma unroll
                    for (int b = 0; b < NB; ++b) {
                        const float4 v = *(const float4*)&lh[b][k0];
                        a0[b] = fma4(W[ly][it],     v, a0[b]);
                        a1[b] = fma4(W[ly][4 + it], v, a1[b]);
                    }
                }
                #pragma unroll
                for (int b = 0; b < NB; ++b) { bfly(a0[b]); bfly(a1[b]); }
                if (lane == 0) {
                    #pragma unroll
                    for (int b = 0; b < NB; ++b) {
                        pp[rw][3][b] = a0[b];
                        pp[rw][4][b] = a1[b];
                    }
                }
            }
            __syncthreads();

            // ---- combine gates: hf1 wave, lanes 0..7 (one batch each) ----
            if (hf == 1 && lane < NB) {
                const int b = lane;
                const float z = 1.f / (1.f + expf(-(pp[rw][0][b] + pp[rw][3][b]
                                                    + gB[ly * 2048 + j])));
                const float r = 1.f / (1.f + expf(-(pp[rw][1][b] + pp[rw][4][b]
                                                    + gB[ly * 2048 + 1024 + j])));
                zz[rw][b] = z;
                rbuf[b * DIM + j] = r;
            }
            gbar(bar, ep, dead);

            // ---- stage rh = r * h_old -> lx ----
            #pragma unroll
            for (int q = 0; q < 4; ++q) {
                int e = q * SCAN_THREADS + tid;
                float4 r4 = ((const float4*)rbuf)[e];
                float4 h4 = ((const float4*)&lh[0][0])[e];
                float4 p;
                p.x = r4.x * h4.x; p.y = r4.y * h4.y;
                p.z = r4.z * h4.z; p.w = r4.w * h4.w;
                ((float4*)&lx[0][0])[e] = p;
            }
            __syncthreads();

            // ---- Phase B: candB (hf1 only) + state update ----
            if (hf == 1) {
                #pragma unroll
                for (int b = 0; b < NB; ++b) a2[b] = 0.f;
                #pragma unroll
                for (int it = 0; it < 4; ++it) {
                    const int k0 = it * 256 + lane * 4;
                    #pragma unroll
                    for (int b = 0; b < NB; ++b) {
                        const float4 v = *(const float4*)&lx[b][k0];
                        a2[b] = fma4(W[ly][8 + it], v, a2[b]);
                    }
                }
                #pragma unroll
                for (int b = 0; b < NB; ++b) bfly(a2[b]);
                if (lane == 0) {
                    #pragma unroll
                    for (int b = 0; b < NB; ++b) pp[rw][3][b] = a2[b];
                }
                // same-wave LDS RAW; compiler inserts lgkmcnt wait
                if (lane < NB) {
                    const int b = lane;
                    const float cand = tanhf(pp[rw][2][b] + pp[rw][3][b]
                                             + cB[ly * DIM + j]);
                    const float z    = zz[rw][b];
                    const float hold = lh[b][j];
                    const float hn   = z * hold + (1.f - z) * cand;
                    hWp[(ly * NB + b) * DIM + j] = hn;
                    if (ly == NLAYER - 1)
                        ysf[((size_t)b * SEQ + t) * DIM + j] = hn;
                }
            }
            gbar(bar, ep, dead);
        }
    }

    if (dead && threadIdx.x == 0)
        ysf[blockIdx.x] = 1.0e8f;
}

// ---------------------------------------------------------------------------
// Logits GEMM (unchanged): C[m][n] = sum_k ys[m][k] * outW[n][k]
// ---------------------------------------------------------------------------
#define BM 128
#define BN 128
#define BK 64

__global__ void __launch_bounds__(256) out_gemm(
    const float* __restrict__ A,   // [4096][1024]  fp32
    const float* __restrict__ B,   // [32000][1024] fp32
    float* __restrict__ C)         // [4096][32000]
{
    __shared__ __hip_bfloat16 At[BM][BK + 8];
    __shared__ __hip_bfloat16 Bt[BN][BK + 8];

    const int tid  = threadIdx.x;
    const int lane = tid & 63;
    const int wv   = tid >> 6;
    const int wm   = wv >> 1, wn = wv & 1;
    const int m0   = blockIdx.y * BM;
    const int n0   = blockIdx.x * BN;

    f32x4 acc[4][4];
    #pragma unroll
    for (int i = 0; i < 4; ++i)
        #pragma unroll
        for (int jj = 0; jj < 4; ++jj)
            acc[i][jj] = (f32x4){0.f, 0.f, 0.f, 0.f};

    const int srow = tid >> 3;           // 0..31
    const int scol = (tid & 7) * 8;      // 0..56
    const int l15  = lane & 15;
    const int l4   = lane >> 4;

    for (int kt = 0; kt < DIM / BK; ++kt) {
        const int k0 = kt * BK;
        #pragma unroll
        for (int rnd = 0; rnd < 4; ++rnd) {
            const int row = rnd * 32 + srow;
            *(u16x8*)&At[row][scol] =
                cvt8_bf16(&A[(size_t)(m0 + row) * DIM + k0 + scol]);
            *(u16x8*)&Bt[row][scol] =
                cvt8_bf16(&B[(size_t)(n0 + row) * DIM + k0 + scol]);
        }
        __syncthreads();
        #pragma unroll
        for (int ks = 0; ks < 2; ++ks) {
            bf16x8 av[4], bv[4];
            #pragma unroll
            for (int i = 0; i < 4; ++i) {
                av[i] = *(const bf16x8*)&At[wm * 64 + i * 16 + l15][ks * 32 + l4 * 8];
                bv[i] = *(const bf16x8*)&Bt[wn * 64 + i * 16 + l15][ks * 32 + l4 * 8];
            }
            #pragma unroll
            for (int i = 0; i < 4; ++i)
                #pragma unroll
                for (int jj = 0; jj < 4; ++jj)
                    acc[i][jj] = __builtin_amdgcn_mfma_f32_16x16x32_bf16(
                        av[i], bv[jj], acc[i][jj], 0, 0, 0);
        }
        __syncthreads();
    }

    const int rq = l4 * 4;
    #pragma unroll
    for (int i = 0; i < 4; ++i) {
        const int rbase = m0 + wm * 64 + i * 16 + rq;
        #pragma unroll
        for (int jj = 0; jj < 4; ++jj) {
            const int col = n0 + wn * 64 + jj * 16 + l15;
            #pragma unroll
            for (int r2 = 0; r2 < 4; ++r2)
                C[(size_t)(rbase + r2) * VOCAB + col] = acc[i][jj][r2];
        }
    }
}

// ---------------------------------------------------------------------------
extern "C" void kernel_launch(void* const* d_in, const int* in_sizes, int n_in,
                              void* d_out, int out_size, void* d_ws, size_t ws_size,
                              hipStream_t stream)
{
    (void)in_sizes; (void)n_in; (void)out_size; (void)ws_size;
    const int*   ids  = (const int*)  d_in[0];
    const float* embW = (const float*)d_in[1];
    const float* hst  = (const float*)d_in[2];
    const float* gW   = (const float*)d_in[3];
    const float* gB   = (const float*)d_in[4];
    const float* cW   = (const float*)d_in[5];
    const float* cB   = (const float*)d_in[6];
    const float* outW = (const float*)d_in[7];
    float* logits = (float*)d_out;

    // workspace carve-up (total ~16.6 MiB)
    char* ws = (char*)d_ws;
    unsigned* bar  = (unsigned*)ws;                     // 4 KiB
    float*    rbuf = (float*)(ws + 4096);               // 32 KiB
    float*    hbuf = (float*)(ws + 4096 + 32768);       // 256 KiB
    float*    ysf  = (float*)(ws + 4096 + 32768 + 262144);   // 16 MiB

    // 1) zero barrier counters
    bar_init_kernel<<<dim3(1), dim3(1024), 0, stream>>>(bar);

    // 2) persistent-weight GRU scan (row-split wave pairs, fp32 weights in VGPRs)
    gru_scan<<<dim3(SCAN_BLOCKS), dim3(SCAN_THREADS), 0, stream>>>(
        ids, embW, hst, gW, gB, cW, cB, hbuf, rbuf, ysf, bar);

    // 3) logits GEMM
    out_gemm<<<dim3(VOCAB / BN, (NB * SEQ) / BM), dim3(256), 0, stream>>>(ysf, outW, logits);
}

// Round 7
// 56498.663 us; speedup vs baseline: 1.3814x; 1.3814x over previous
//
#include <hip/hip_runtime.h>
#include <hip/hip_bf16.h>

#define VOCAB  32000
#define DIM    1024
#define NLAYER 4
#define NB     8
#define SEQ    512

#define SCAN_BLOCKS  256
#define SCAN_THREADS 512   // 8 waves = 4 rows x 2 half-waves; 2048 waves total

typedef __attribute__((ext_vector_type(8))) short          bf16x8;
typedef __attribute__((ext_vector_type(4))) float          f32x4;
typedef __attribute__((ext_vector_type(8))) unsigned short u16x8;
typedef __attribute__((ext_vector_type(2))) _Float16       h2f;
typedef __attribute__((ext_vector_type(4))) _Float16       h4f;

__device__ __forceinline__ void bfly(float& v) {
    #pragma unroll
    for (int off = 32; off > 0; off >>= 1) v += __shfl_xor(v, off);
}

__device__ __forceinline__ u16x8 cvt8_bf16(const float* p) {
    float4 f0 = *(const float4*)p;
    float4 f1 = *(const float4*)(p + 4);
    union { __hip_bfloat16 h[8]; u16x8 v; } u;
    u.h[0] = __float2bfloat16(f0.x); u.h[1] = __float2bfloat16(f0.y);
    u.h[2] = __float2bfloat16(f0.z); u.h[3] = __float2bfloat16(f0.w);
    u.h[4] = __float2bfloat16(f1.x); u.h[5] = __float2bfloat16(f1.y);
    u.h[6] = __float2bfloat16(f1.z); u.h[7] = __float2bfloat16(f1.w);
    return u.v;
}

// ---------------------------------------------------------------------------
__global__ void bar_init_kernel(unsigned* __restrict__ bar) {
    bar[threadIdx.x] = 0u;   // 1024 words
}

// ---------------------------------------------------------------------------
// Two-level monotonic grid barrier, AGENT scope (proven rounds 3-6).
// ---------------------------------------------------------------------------
__device__ __forceinline__ void gbar(unsigned* bar, unsigned& ep, bool& dead) {
    __syncthreads();
    if (threadIdx.x == 0 && !dead) {
        unsigned* root = bar;
        unsigned* leaf = bar + 32 + 32 * (blockIdx.x & 7);
        unsigned old = __hip_atomic_fetch_add(leaf, 1u, __ATOMIC_ACQ_REL,
                                              __HIP_MEMORY_SCOPE_AGENT);
        if (old == ep * (SCAN_BLOCKS / 8) - 1)
            __hip_atomic_fetch_add(root, 1u, __ATOMIC_ACQ_REL,
                                   __HIP_MEMORY_SCOPE_AGENT);
        unsigned guard = 0;
        while (__hip_atomic_load(root, __ATOMIC_RELAXED,
                                 __HIP_MEMORY_SCOPE_AGENT) < ep * 8u) {
            __builtin_amdgcn_s_sleep(2);
            if (++guard > (1u << 19)) { dead = true; break; }
        }
        (void)__hip_atomic_load(root, __ATOMIC_ACQUIRE,
                                __HIP_MEMORY_SCOPE_AGENT);
    }
    __syncthreads();
    ep++;
}

// ---------------------------------------------------------------------------
// Persistent-weight GRU scan, fp16 weights in VGPRs + v_dot2_f32_f16.
// Topology as round 6: block bk owns rows j = bk*4 + rw; wave wv: rw=wv>>1,
// hf=wv&1 (x-half / h-half of k). Per wave: 3 row-types x 4 layers x 1024
// halves / 64 lanes = 96 half2 VGPRs, preloaded once, pinned via asm
// keep-alive (prevents the remat that killed round 6 and the spill that
// killed round 5).
// Activations are staged to LDS as fp16; dot products accumulate fp32 via
// fdot2; gates/tanh/state update all fp32; h state in global stays fp32.
// ---------------------------------------------------------------------------
__global__ void __launch_bounds__(SCAN_THREADS, 2) gru_scan(
    const int*   __restrict__ ids,     // [NB][SEQ]
    const float* __restrict__ embW,    // [VOCAB][DIM]
    const float* __restrict__ hstart,  // [NLAYER][DIM]
    const float* __restrict__ gW,      // [NLAYER][2*DIM][2*DIM]
    const float* __restrict__ gB,      // [NLAYER][2*DIM]
    const float* __restrict__ cW,      // [NLAYER][DIM][2*DIM]
    const float* __restrict__ cB,      // [NLAYER][DIM]
    float* __restrict__ hbuf,          // [2][NLAYER][NB][DIM]
    float* __restrict__ rbuf,          // [NB][DIM]
    float* __restrict__ ysf,           // [NB][SEQ][DIM] fp32
    unsigned* __restrict__ bar)
{
    __shared__ _Float16 lxh[NB][DIM];  // 16KB: xin (A) / rh (B), fp16
    __shared__ _Float16 lhh[NB][DIM];  // 16KB: old h, fp16 (dot input only)
    __shared__ float    pp[4][5][NB];  // partials: zx,rx,cx | zh,rh
    __shared__ float    zz[4][NB];     // combined z gate

    const int tid  = threadIdx.x;
    const int lane = tid & 63;
    const int wv   = tid >> 6;         // 0..7
    const int rw   = wv >> 1;          // row within block 0..3
    const int hf   = wv & 1;           // 0: x-half, 1: h-half of k
    const int j    = blockIdx.x * 4 + rw;

    // ---- persistent fp16 weight preload: 96 half2 VGPRs/lane ----
    h2f Wz[NLAYER][8], Wr[NLAYER][8], Wc[NLAYER][8];
    {
        const int kb = hf * 1024;
        #pragma unroll
        for (int ly = 0; ly < NLAYER; ++ly) {
            const float* wz = gW + ((size_t)ly * 2048 + j) * 2048 + kb;
            const float* wr = gW + ((size_t)ly * 2048 + 1024 + j) * 2048 + kb;
            const float* wc = cW + ((size_t)ly * 1024 + j) * 2048 + kb;
            #pragma unroll
            for (int it = 0; it < 4; ++it) {
                const int k0 = it * 256 + lane * 4;
                float4 fz = *(const float4*)(wz + k0);
                float4 fr = *(const float4*)(wr + k0);
                float4 fc = *(const float4*)(wc + k0);
                Wz[ly][2*it]   = h2f{(_Float16)fz.x, (_Float16)fz.y};
                Wz[ly][2*it+1] = h2f{(_Float16)fz.z, (_Float16)fz.w};
                Wr[ly][2*it]   = h2f{(_Float16)fr.x, (_Float16)fr.y};
                Wr[ly][2*it+1] = h2f{(_Float16)fr.z, (_Float16)fr.w};
                Wc[ly][2*it]   = h2f{(_Float16)fc.x, (_Float16)fc.y};
                Wc[ly][2*it+1] = h2f{(_Float16)fc.z, (_Float16)fc.w};
            }
        }
        // pin: opaque asm makes remat impossible; values must stay in VGPRs
        #pragma unroll
        for (int ly = 0; ly < NLAYER; ++ly)
            #pragma unroll
            for (int i = 0; i < 8; ++i) {
                asm volatile("" : "+v"(Wz[ly][i]));
                asm volatile("" : "+v"(Wr[ly][i]));
                asm volatile("" : "+v"(Wc[ly][i]));
            }
    }

    unsigned ep = 1;
    bool dead = false;

    // init h parity-0 buffer: hbuf[0][layer][b][d] = hstart[layer][d]
    {
        int g = blockIdx.x * SCAN_THREADS + tid;
        if (g < NLAYER * NB * DIM)
            hbuf[g] = hstart[((g >> 13) << 10) | (g & (DIM - 1))];
    }
    gbar(bar, ep, dead);

    for (int t = 0; t < SEQ; ++t) {
        const float* hR  = hbuf + (t & 1)       * (NLAYER * NB * DIM);
        float*       hWp = hbuf + ((t & 1) ^ 1) * (NLAYER * NB * DIM);

        #pragma unroll
        for (int ly = 0; ly < NLAYER; ++ly) {
            // ---- stage xin -> lxh and h_old -> lhh as fp16 ----
            // 2048 half4 units per buffer; 4 units per thread.
            if (ly == 0) {
                #pragma unroll
                for (int q = 0; q < 4; ++q) {
                    int e = q * SCAN_THREADS + tid;      // 0..2047
                    int b = e >> 8;
                    int row = ids[b * SEQ + t];
                    float4 f = ((const float4*)(embW + (size_t)row * DIM))[e & 255];
                    ((h4f*)&lxh[0][0])[e] =
                        h4f{(_Float16)f.x, (_Float16)f.y, (_Float16)f.z, (_Float16)f.w};
                }
            } else {
                const float* src = hWp + (ly - 1) * NB * DIM;
                #pragma unroll
                for (int q = 0; q < 4; ++q) {
                    int e = q * SCAN_THREADS + tid;
                    float4 f = ((const float4*)src)[e];
                    ((h4f*)&lxh[0][0])[e] =
                        h4f{(_Float16)f.x, (_Float16)f.y, (_Float16)f.z, (_Float16)f.w};
                }
            }
            {
                const float* src = hR + ly * NB * DIM;
                #pragma unroll
                for (int q = 0; q < 4; ++q) {
                    int e = q * SCAN_THREADS + tid;
                    float4 f = ((const float4*)src)[e];
                    ((h4f*)&lhh[0][0])[e] =
                        h4f{(_Float16)f.x, (_Float16)f.y, (_Float16)f.z, (_Float16)f.w};
                }
            }
            __syncthreads();

            // ---- Phase A: partial dots over this wave's k-half ----
            float a0[NB] = {0,0,0,0,0,0,0,0};   // z
            float a1[NB] = {0,0,0,0,0,0,0,0};   // r
            float a2[NB] = {0,0,0,0,0,0,0,0};   // c (hf0) / candB (hf1 phase B)

            if (hf == 0) {
                #pragma unroll
                for (int it = 0; it < 4; ++it) {
                    const int k0 = it * 256 + lane * 4;
                    #pragma unroll
                    for (int b = 0; b < NB; ++b) {
                        h4f v = *(const h4f*)&lxh[b][k0];
                        h2f v01 = h2f{v[0], v[1]};
                        h2f v23 = h2f{v[2], v[3]};
                        a0[b] = __builtin_amdgcn_fdot2(Wz[ly][2*it],   v01, a0[b], false);
                        a0[b] = __builtin_amdgcn_fdot2(Wz[ly][2*it+1], v23, a0[b], false);
                        a1[b] = __builtin_amdgcn_fdot2(Wr[ly][2*it],   v01, a1[b], false);
                        a1[b] = __builtin_amdgcn_fdot2(Wr[ly][2*it+1], v23, a1[b], false);
                        a2[b] = __builtin_amdgcn_fdot2(Wc[ly][2*it],   v01, a2[b], false);
                        a2[b] = __builtin_amdgcn_fdot2(Wc[ly][2*it+1], v23, a2[b], false);
                    }
                }
                #pragma unroll
                for (int b = 0; b < NB; ++b) { bfly(a0[b]); bfly(a1[b]); bfly(a2[b]); }
                if (lane == 0) {
                    #pragma unroll
                    for (int b = 0; b < NB; ++b) {
                        pp[rw][0][b] = a0[b];
                        pp[rw][1][b] = a1[b];
                        pp[rw][2][b] = a2[b];
                    }
                }
            } else {
                #pragma unroll
                for (int it = 0; it < 4; ++it) {
                    const int k0 = it * 256 + lane * 4;
                    #pragma unroll
                    for (int b = 0; b < NB; ++b) {
                        h4f v = *(const h4f*)&lhh[b][k0];
                        h2f v01 = h2f{v[0], v[1]};
                        h2f v23 = h2f{v[2], v[3]};
                        a0[b] = __builtin_amdgcn_fdot2(Wz[ly][2*it],   v01, a0[b], false);
                        a0[b] = __builtin_amdgcn_fdot2(Wz[ly][2*it+1], v23, a0[b], false);
                        a1[b] = __builtin_amdgcn_fdot2(Wr[ly][2*it],   v01, a1[b], false);
                        a1[b] = __builtin_amdgcn_fdot2(Wr[ly][2*it+1], v23, a1[b], false);
                    }
                }
                #pragma unroll
                for (int b = 0; b < NB; ++b) { bfly(a0[b]); bfly(a1[b]); }
                if (lane == 0) {
                    #pragma unroll
                    for (int b = 0; b < NB; ++b) {
                        pp[rw][3][b] = a0[b];
                        pp[rw][4][b] = a1[b];
                    }
                }
            }
            __syncthreads();

            // ---- combine gates: hf1 wave, lanes 0..7 (one batch each) ----
            if (hf == 1 && lane < NB) {
                const int b = lane;
                const float z = 1.f / (1.f + expf(-(pp[rw][0][b] + pp[rw][3][b]
                                                    + gB[ly * 2048 + j])));
                const float r = 1.f / (1.f + expf(-(pp[rw][1][b] + pp[rw][4][b]
                                                    + gB[ly * 2048 + 1024 + j])));
                zz[rw][b] = z;
                rbuf[b * DIM + j] = r;
            }
            gbar(bar, ep, dead);

            // ---- stage rh = r * h_old -> lxh (fp32 product, fp16 store) ----
            {
                const float* hsrc = hR + ly * NB * DIM;
                #pragma unroll
                for (int q = 0; q < 4; ++q) {
                    int e = q * SCAN_THREADS + tid;
                    float4 r4 = ((const float4*)rbuf)[e];
                    float4 h4 = ((const float4*)hsrc)[e];
                    ((h4f*)&lxh[0][0])[e] = h4f{
                        (_Float16)(r4.x * h4.x), (_Float16)(r4.y * h4.y),
                        (_Float16)(r4.z * h4.z), (_Float16)(r4.w * h4.w)};
                }
            }
            __syncthreads();

            // ---- Phase B: candB (hf1 only) + state update ----
            if (hf == 1) {
                #pragma unroll
                for (int b = 0; b < NB; ++b) a2[b] = 0.f;
                #pragma unroll
                for (int it = 0; it < 4; ++it) {
                    const int k0 = it * 256 + lane * 4;
                    #pragma unroll
                    for (int b = 0; b < NB; ++b) {
                        h4f v = *(const h4f*)&lxh[b][k0];
                        h2f v01 = h2f{v[0], v[1]};
                        h2f v23 = h2f{v[2], v[3]};
                        a2[b] = __builtin_amdgcn_fdot2(Wc[ly][2*it],   v01, a2[b], false);
                        a2[b] = __builtin_amdgcn_fdot2(Wc[ly][2*it+1], v23, a2[b], false);
                    }
                }
                #pragma unroll
                for (int b = 0; b < NB; ++b) bfly(a2[b]);
                if (lane == 0) {
                    #pragma unroll
                    for (int b = 0; b < NB; ++b) pp[rw][3][b] = a2[b];
                }
                // same-wave LDS RAW: in-order per wave, compiler adds lgkmcnt
                if (lane < NB) {
                    const int b = lane;
                    const float cand = tanhf(pp[rw][2][b] + pp[rw][3][b]
                                             + cB[ly * DIM + j]);
                    const float z    = zz[rw][b];
                    const float hold = hR[ly * NB * DIM + b * DIM + j];  // fp32 state
                    const float hn   = z * hold + (1.f - z) * cand;
                    hWp[(ly * NB + b) * DIM + j] = hn;
                    if (ly == NLAYER - 1)
                        ysf[((size_t)b * SEQ + t) * DIM + j] = hn;
                }
            }
            gbar(bar, ep, dead);
        }
    }

    if (dead && threadIdx.x == 0)
        ysf[blockIdx.x] = 1.0e8f;
}

// ---------------------------------------------------------------------------
// Logits GEMM (unchanged): C[m][n] = sum_k ys[m][k] * outW[n][k]
// ---------------------------------------------------------------------------
#define BM 128
#define BN 128
#define BK 64

__global__ void __launch_bounds__(256) out_gemm(
    const float* __restrict__ A,   // [4096][1024]  fp32
    const float* __restrict__ B,   // [32000][1024] fp32
    float* __restrict__ C)         // [4096][32000]
{
    __shared__ __hip_bfloat16 At[BM][BK + 8];
    __shared__ __hip_bfloat16 Bt[BN][BK + 8];

    const int tid  = threadIdx.x;
    const int lane = tid & 63;
    const int wv   = tid >> 6;
    const int wm   = wv >> 1, wn = wv & 1;
    const int m0   = blockIdx.y * BM;
    const int n0   = blockIdx.x * BN;

    f32x4 acc[4][4];
    #pragma unroll
    for (int i = 0; i < 4; ++i)
        #pragma unroll
        for (int jj = 0; jj < 4; ++jj)
            acc[i][jj] = (f32x4){0.f, 0.f, 0.f, 0.f};

    const int srow = tid >> 3;           // 0..31
    const int scol = (tid & 7) * 8;      // 0..56
    const int l15  = lane & 15;
    const int l4   = lane >> 4;

    for (int kt = 0; kt < DIM / BK; ++kt) {
        const int k0 = kt * BK;
        #pragma unroll
        for (int rnd = 0; rnd < 4; ++rnd) {
            const int row = rnd * 32 + srow;
            *(u16x8*)&At[row][scol] =
                cvt8_bf16(&A[(size_t)(m0 + row) * DIM + k0 + scol]);
            *(u16x8*)&Bt[row][scol] =
                cvt8_bf16(&B[(size_t)(n0 + row) * DIM + k0 + scol]);
        }
        __syncthreads();
        #pragma unroll
        for (int ks = 0; ks < 2; ++ks) {
            bf16x8 av[4], bv[4];
            #pragma unroll
            for (int i = 0; i < 4; ++i) {
                av[i] = *(const bf16x8*)&At[wm * 64 + i * 16 + l15][ks * 32 + l4 * 8];
                bv[i] = *(const bf16x8*)&Bt[wn * 64 + i * 16 + l15][ks * 32 + l4 * 8];
            }
            #pragma unroll
            for (int i = 0; i < 4; ++i)
                #pragma unroll
                for (int jj = 0; jj < 4; ++jj)
                    acc[i][jj] = __builtin_amdgcn_mfma_f32_16x16x32_bf16(
                        av[i], bv[jj], acc[i][jj], 0, 0, 0);
        }
        __syncthreads();
    }

    const int rq = l4 * 4;
    #pragma unroll
    for (int i = 0; i < 4; ++i) {
        const int rbase = m0 + wm * 64 + i * 16 + rq;
        #pragma unroll
        for (int jj = 0; jj < 4; ++jj) {
            const int col = n0 + wn * 64 + jj * 16 + l15;
            #pragma unroll
            for (int r2 = 0; r2 < 4; ++r2)
                C[(size_t)(rbase + r2) * VOCAB + col] = acc[i][jj][r2];
        }
    }
}

// ---------------------------------------------------------------------------
extern "C" void kernel_launch(void* const* d_in, const int* in_sizes, int n_in,
                              void* d_out, int out_size, void* d_ws, size_t ws_size,
                              hipStream_t stream)
{
    (void)in_sizes; (void)n_in; (void)out_size; (void)ws_size;
    const int*   ids  = (const int*)  d_in[0];
    const float* embW = (const float*)d_in[1];
    const float* hst  = (const float*)d_in[2];
    const float* gW   = (const float*)d_in[3];
    const float* gB   = (const float*)d_in[4];
    const float* cW   = (const float*)d_in[5];
    const float* cB   = (const float*)d_in[6];
    const float* outW = (const float*)d_in[7];
    float* logits = (float*)d_out;

    // workspace carve-up (total ~16.6 MiB)
    char* ws = (char*)d_ws;
    unsigned* bar  = (unsigned*)ws;                     // 4 KiB
    float*    rbuf = (float*)(ws + 4096);               // 32 KiB
    float*    hbuf = (float*)(ws + 4096 + 32768);       // 256 KiB
    float*    ysf  = (float*)(ws + 4096 + 32768 + 262144);   // 16 MiB

    // 1) zero barrier counters
    bar_init_kernel<<<dim3(1), dim3(1024), 0, stream>>>(bar);

    // 2) persistent-weight GRU scan (fp16 weights in VGPRs, fdot2)
    gru_scan<<<dim3(SCAN_BLOCKS), dim3(SCAN_THREADS), 0, stream>>>(
        ids, embW, hst, gW, gB, cW, cB, hbuf, rbuf, ysf, bar);

    // 3) logits GEMM
    out_gemm<<<dim3(VOCAB / BN, (NB * SEQ) / BM), dim3(256), 0, stream>>>(ysf, outW, logits);
}

// Round 8
// 21999.689 us; speedup vs baseline: 3.5475x; 2.5682x over previous
//
#include <hip/hip_runtime.h>
#include <hip/hip_bf16.h>

#define VOCAB  32000
#define DIM    1024
#define NLAYER 4
#define NB     8
#define SEQ    512

#define NGROUP       4
#define GBLKS        64                    // blocks per layer-group
#define SCAN_BLOCKS  (NGROUP * GBLKS)      // 256
#define SCAN_THREADS 512                   // 8 waves; wave owns 2 full rows

typedef __attribute__((ext_vector_type(8))) short          bf16x8;
typedef __attribute__((ext_vector_type(4))) float          f32x4;
typedef __attribute__((ext_vector_type(8))) unsigned short u16x8;
typedef __attribute__((ext_vector_type(2))) _Float16       h2f;
typedef __attribute__((ext_vector_type(4))) _Float16       h4f;

__device__ __forceinline__ void bfly(float& v) {
    #pragma unroll
    for (int off = 32; off > 0; off >>= 1) v += __shfl_xor(v, off);
}

__device__ __forceinline__ u16x8 cvt8_bf16(const float* p) {
    float4 f0 = *(const float4*)p;
    float4 f1 = *(const float4*)(p + 4);
    union { __hip_bfloat16 h[8]; u16x8 v; } u;
    u.h[0] = __float2bfloat16(f0.x); u.h[1] = __float2bfloat16(f0.y);
    u.h[2] = __float2bfloat16(f0.z); u.h[3] = __float2bfloat16(f0.w);
    u.h[4] = __float2bfloat16(f1.x); u.h[5] = __float2bfloat16(f1.y);
    u.h[6] = __float2bfloat16(f1.z); u.h[7] = __float2bfloat16(f1.w);
    return u.v;
}

// ---------------------------------------------------------------------------
__global__ void bar_init_kernel(unsigned* __restrict__ bar) {
    bar[threadIdx.x]        = 0u;
    bar[threadIdx.x + 1024] = 0u;   // 2048 words = 8 KiB
}

// ---- agent-scope atomic helpers (cross-XCD safe; proven rounds 3-7) ----
__device__ __forceinline__ unsigned aadd(unsigned* p) {
    return __hip_atomic_fetch_add(p, 1u, __ATOMIC_ACQ_REL, __HIP_MEMORY_SCOPE_AGENT);
}
__device__ __forceinline__ unsigned aldr(unsigned* p) {
    return __hip_atomic_load(p, __ATOMIC_RELAXED, __HIP_MEMORY_SCOPE_AGENT);
}
__device__ __forceinline__ unsigned alda(unsigned* p) {
    return __hip_atomic_load(p, __ATOMIC_ACQUIRE, __HIP_MEMORY_SCOPE_AGENT);
}
__device__ __forceinline__ void asta(unsigned* p, unsigned v) {
    __hip_atomic_store(p, v, __ATOMIC_RELEASE, __HIP_MEMORY_SCOPE_AGENT);
}

// ---------------------------------------------------------------------------
// Per-group barrier: 64 blocks, 8-leaf tree (8 arrivals/leaf, 8 leaf-adds to
// root). Last root arriver optionally release-stores a flag (prod/cons
// counter). Counter layout in bar (word = idx*32, one line apart):
//   group g: root = g*9, leaves = g*9+1+l (l=0..7); prod[g]=40+g; cons[g]=48+g.
// ---------------------------------------------------------------------------
__device__ __forceinline__ void gbar_grp(unsigned* bar, int g, int bkg,
                                         unsigned& ep, bool& dead,
                                         unsigned* flagp, unsigned flagv) {
    __syncthreads();
    if (threadIdx.x == 0 && !dead) {
        unsigned* root = bar + (g * 9) * 32;
        unsigned* leaf = bar + (g * 9 + 1 + (bkg & 7)) * 32;
        unsigned old = aadd(leaf);
        if (old == ep * 8u - 1u) {
            unsigned rold = aadd(root);
            if (rold == ep * 8u - 1u && flagp) asta(flagp, flagv);
        }
        unsigned guard = 0;
        while (aldr(root) < ep * 8u) {
            __builtin_amdgcn_s_sleep(2);
            if (++guard > (1u << 19)) { dead = true; break; }
        }
        (void)alda(root);   // acquire: invalidate caches before peer data reads
    }
    __syncthreads();
    ep++;
}

__device__ __forceinline__ void wait_ge(unsigned* p, unsigned tgt, bool& dead) {
    if (dead) return;
    unsigned guard = 0;
    while (alda(p) < tgt) {
        __builtin_amdgcn_s_sleep(2);
        if (++guard > (1u << 18)) { dead = true; break; }
    }
}

// ---------------------------------------------------------------------------
// Layer-pipelined persistent-weight GRU scan.
// Group g = blockIdx>>6 owns layer g forever; 64 blocks/group; wave wv owns
// rows j0=bkg*16+wv*2, j0+1 FULLY (k in [0,2048)): W[2][3][16] h2 = 96 VGPR
// fp16 weights, pinned. Complete dots per wave -> no partial exchange.
// h ring buffer 4 deep: h(t) lives in slot t&3; h(-1) in slot 3.
// Flow control: xin ready  <=> prod[g-1] >= t+1 (set by g-1's bar2)
//              slot free   <=> cons[g+1] >= t-3 (set by g+1's bar1)
// ---------------------------------------------------------------------------
__global__ void __launch_bounds__(SCAN_THREADS)
__attribute__((amdgpu_waves_per_eu(2, 2)))
gru_scan(
    const int*   __restrict__ ids,     // [NB][SEQ]
    const float* __restrict__ embW,    // [VOCAB][DIM]
    const float* __restrict__ hstart,  // [NLAYER][DIM]
    const float* __restrict__ gW,      // [NLAYER][2*DIM][2*DIM]
    const float* __restrict__ gB,      // [NLAYER][2*DIM]
    const float* __restrict__ cW,      // [NLAYER][DIM][2*DIM]
    const float* __restrict__ cB,      // [NLAYER][DIM]
    float* __restrict__ hbuf,          // [4][NLAYER][NB][DIM]
    float* __restrict__ rbuf,          // [NGROUP][NB][DIM]
    float* __restrict__ ysf,           // [NB][SEQ][DIM] fp32
    unsigned* __restrict__ bar)
{
    __shared__ _Float16 lxh[NB][DIM];   // 16KB: xin (A) / rh (B)
    __shared__ _Float16 lhh[NB][DIM];   // 16KB: own h_old (dot input)
    __shared__ float rs[8][2][NB];      // r  per wave/row/batch
    __shared__ float zs[8][2][NB];      // z
    __shared__ float cs[8][2][NB];      // candA then candA+candB

    const int tid  = threadIdx.x;
    const int lane = tid & 63;
    const int wv   = tid >> 6;               // 0..7
    const int g    = blockIdx.x >> 6;        // layer group 0..3
    const int bkg  = blockIdx.x & (GBLKS-1); // 0..63
    const int j0   = bkg * 16 + wv * 2;      // wave's first row

    // ---- persistent fp16 weights: [row][type z,r,c][16 h2]; idx 0..7 = x-half,
    //      8..15 = h-half (k = it*256+lane*4 within each half) ----
    h2f W[2][3][16];
    float bzv[2], brv[2], cbv[2];
    #pragma unroll
    for (int rr = 0; rr < 2; ++rr) {
        const int j = j0 + rr;
        const float* wz = gW + ((size_t)g * 2048 + j) * 2048;
        const float* wr = gW + ((size_t)g * 2048 + 1024 + j) * 2048;
        const float* wc = cW + ((size_t)g * 1024 + j) * 2048;
        #pragma unroll
        for (int it = 0; it < 4; ++it) {
            const int k0 = it * 256 + lane * 4;
            float4 f;
            f = *(const float4*)(wz + k0);
            W[rr][0][2*it]     = h2f{(_Float16)f.x, (_Float16)f.y};
            W[rr][0][2*it+1]   = h2f{(_Float16)f.z, (_Float16)f.w};
            f = *(const float4*)(wz + 1024 + k0);
            W[rr][0][8+2*it]   = h2f{(_Float16)f.x, (_Float16)f.y};
            W[rr][0][9+2*it]   = h2f{(_Float16)f.z, (_Float16)f.w};
            f = *(const float4*)(wr + k0);
            W[rr][1][2*it]     = h2f{(_Float16)f.x, (_Float16)f.y};
            W[rr][1][2*it+1]   = h2f{(_Float16)f.z, (_Float16)f.w};
            f = *(const float4*)(wr + 1024 + k0);
            W[rr][1][8+2*it]   = h2f{(_Float16)f.x, (_Float16)f.y};
            W[rr][1][9+2*it]   = h2f{(_Float16)f.z, (_Float16)f.w};
            f = *(const float4*)(wc + k0);
            W[rr][2][2*it]     = h2f{(_Float16)f.x, (_Float16)f.y};
            W[rr][2][2*it+1]   = h2f{(_Float16)f.z, (_Float16)f.w};
            f = *(const float4*)(wc + 1024 + k0);
            W[rr][2][8+2*it]   = h2f{(_Float16)f.x, (_Float16)f.y};
            W[rr][2][9+2*it]   = h2f{(_Float16)f.z, (_Float16)f.w};
        }
        bzv[rr] = gB[g * 2048 + j];
        brv[rr] = gB[g * 2048 + 1024 + j];
        cbv[rr] = cB[g * DIM + j];
    }
    #pragma unroll
    for (int rr = 0; rr < 2; ++rr)
        #pragma unroll
        for (int ty = 0; ty < 3; ++ty)
            #pragma unroll
            for (int i = 0; i < 16; ++i)
                asm volatile("" : "+v"(W[rr][ty][i]));   // pin: no remat/spill

    unsigned ep = 1;
    bool dead = false;

    unsigned* prodp    = bar + (40 + g) * 32;
    unsigned* consp    = bar + (48 + g) * 32;
    unsigned* prodprev = (g > 0)          ? bar + (40 + g - 1) * 32 : nullptr;
    unsigned* consnext = (g < NGROUP - 1) ? bar + (48 + g + 1) * 32 : nullptr;

    float* rbufg = rbuf + (size_t)g * NB * DIM;

    // init own layer h(-1) into slot 3
    if (tid < 128) {
        int e = bkg * 128 + tid;   // 0..8191
        hbuf[((size_t)3 * NLAYER + g) * NB * DIM + e] = hstart[g * DIM + (e & (DIM - 1))];
    }
    gbar_grp(bar, g, bkg, ep, dead, nullptr, 0u);

    for (int t = 0; t < SEQ; ++t) {
        const int so = (t + 3) & 3;   // h_old slot
        const int sw = t & 3;         // h_new slot
        const float* hsrc = hbuf + ((size_t)so * NLAYER + g) * NB * DIM;
        float*       hdst = hbuf + ((size_t)sw * NLAYER + g) * NB * DIM;

        // ---- flow control ----
        if (tid == 0) {
            if (g > 0)              wait_ge(prodprev, (unsigned)(t + 1), dead);
            if (consnext && t >= 4) wait_ge(consnext, (unsigned)(t - 3), dead);
        }
        __syncthreads();

        // ---- stage xin -> lxh, h_old -> lhh (fp16) ----
        if (g == 0) {
            #pragma unroll
            for (int q = 0; q < 4; ++q) {
                int e = q * SCAN_THREADS + tid;   // 0..2047 h4f units
                int b = e >> 8;
                int row = ids[b * SEQ + t];
                float4 f = ((const float4*)(embW + (size_t)row * DIM))[e & 255];
                ((h4f*)&lxh[0][0])[e] =
                    h4f{(_Float16)f.x, (_Float16)f.y, (_Float16)f.z, (_Float16)f.w};
            }
        } else {
            const float* src = hbuf + ((size_t)sw * NLAYER + (g - 1)) * NB * DIM;
            #pragma unroll
            for (int q = 0; q < 4; ++q) {
                int e = q * SCAN_THREADS + tid;
                float4 f = ((const float4*)src)[e];
                ((h4f*)&lxh[0][0])[e] =
                    h4f{(_Float16)f.x, (_Float16)f.y, (_Float16)f.z, (_Float16)f.w};
            }
        }
        #pragma unroll
        for (int q = 0; q < 4; ++q) {
            int e = q * SCAN_THREADS + tid;
            float4 f = ((const float4*)hsrc)[e];
            ((h4f*)&lhh[0][0])[e] =
                h4f{(_Float16)f.x, (_Float16)f.y, (_Float16)f.z, (_Float16)f.w};
        }
        __syncthreads();

        // ---- Phase A: full z, r, candA dots for 2 rows x 8 batches ----
        float az[2][NB], ar[2][NB], ac[2][NB];
        #pragma unroll
        for (int rr = 0; rr < 2; ++rr)
            #pragma unroll
            for (int b = 0; b < NB; ++b) { az[rr][b] = 0.f; ar[rr][b] = 0.f; ac[rr][b] = 0.f; }

        #pragma unroll
        for (int it = 0; it < 4; ++it) {
            const int k0 = it * 256 + lane * 4;
            #pragma unroll
            for (int b = 0; b < NB; ++b) {
                h4f xv = *(const h4f*)&lxh[b][k0];
                h4f hv = *(const h4f*)&lhh[b][k0];
                h2f x01{xv[0], xv[1]}, x23{xv[2], xv[3]};
                h2f h01{hv[0], hv[1]}, h23{hv[2], hv[3]};
                #pragma unroll
                for (int rr = 0; rr < 2; ++rr) {
                    az[rr][b] = __builtin_amdgcn_fdot2(W[rr][0][2*it],   x01, az[rr][b], false);
                    az[rr][b] = __builtin_amdgcn_fdot2(W[rr][0][2*it+1], x23, az[rr][b], false);
                    az[rr][b] = __builtin_amdgcn_fdot2(W[rr][0][8+2*it], h01, az[rr][b], false);
                    az[rr][b] = __builtin_amdgcn_fdot2(W[rr][0][9+2*it], h23, az[rr][b], false);
                    ar[rr][b] = __builtin_amdgcn_fdot2(W[rr][1][2*it],   x01, ar[rr][b], false);
                    ar[rr][b] = __builtin_amdgcn_fdot2(W[rr][1][2*it+1], x23, ar[rr][b], false);
                    ar[rr][b] = __builtin_amdgcn_fdot2(W[rr][1][8+2*it], h01, ar[rr][b], false);
                    ar[rr][b] = __builtin_amdgcn_fdot2(W[rr][1][9+2*it], h23, ar[rr][b], false);
                    ac[rr][b] = __builtin_amdgcn_fdot2(W[rr][2][2*it],   x01, ac[rr][b], false);
                    ac[rr][b] = __builtin_amdgcn_fdot2(W[rr][2][2*it+1], x23, ac[rr][b], false);
                }
            }
        }
        #pragma unroll
        for (int rr = 0; rr < 2; ++rr)
            #pragma unroll
            for (int b = 0; b < NB; ++b) { bfly(az[rr][b]); bfly(ar[rr][b]); bfly(ac[rr][b]); }

        if (lane == 0) {
            #pragma unroll
            for (int rr = 0; rr < 2; ++rr)
                #pragma unroll
                for (int b = 0; b < NB; ++b) {
                    zs[wv][rr][b] = 1.f / (1.f + expf(-(az[rr][b] + bzv[rr])));
                    rs[wv][rr][b] = 1.f / (1.f + expf(-(ar[rr][b] + brv[rr])));
                    cs[wv][rr][b] = ac[rr][b];
                }
        }
        // publish r (same-wave LDS RAW; lanes 0..7, 2 stores each)
        if (lane < NB) {
            rbufg[lane * DIM + j0]     = rs[wv][0][lane];
            rbufg[lane * DIM + j0 + 1] = rs[wv][1][lane];
        }
        // bar1: r published; also signals xin consumed (cons[g] = t+1)
        gbar_grp(bar, g, bkg, ep, dead, consp, (unsigned)(t + 1));

        // ---- stage rh = r * h_old -> lxh ----
        #pragma unroll
        for (int q = 0; q < 4; ++q) {
            int e = q * SCAN_THREADS + tid;
            float4 r4 = ((const float4*)rbufg)[e];
            float4 h4 = ((const float4*)hsrc)[e];
            ((h4f*)&lxh[0][0])[e] = h4f{
                (_Float16)(r4.x * h4.x), (_Float16)(r4.y * h4.y),
                (_Float16)(r4.z * h4.z), (_Float16)(r4.w * h4.w)};
        }
        __syncthreads();

        // ---- Phase B: candB + state update ----
        float ab[2][NB];
        #pragma unroll
        for (int rr = 0; rr < 2; ++rr)
            #pragma unroll
            for (int b = 0; b < NB; ++b) ab[rr][b] = 0.f;
        #pragma unroll
        for (int it = 0; it < 4; ++it) {
            const int k0 = it * 256 + lane * 4;
            #pragma unroll
            for (int b = 0; b < NB; ++b) {
                h4f pv = *(const h4f*)&lxh[b][k0];
                h2f p01{pv[0], pv[1]}, p23{pv[2], pv[3]};
                #pragma unroll
                for (int rr = 0; rr < 2; ++rr) {
                    ab[rr][b] = __builtin_amdgcn_fdot2(W[rr][2][8+2*it], p01, ab[rr][b], false);
                    ab[rr][b] = __builtin_amdgcn_fdot2(W[rr][2][9+2*it], p23, ab[rr][b], false);
                }
            }
        }
        #pragma unroll
        for (int rr = 0; rr < 2; ++rr)
            #pragma unroll
            for (int b = 0; b < NB; ++b) bfly(ab[rr][b]);

        if (lane == 0) {
            #pragma unroll
            for (int rr = 0; rr < 2; ++rr)
                #pragma unroll
                for (int b = 0; b < NB; ++b) cs[wv][rr][b] += ab[rr][b];
        }
        if (lane < NB) {   // same-wave LDS RAW after lane-0 writes
            const int b = lane;
            #pragma unroll
            for (int rr = 0; rr < 2; ++rr) {
                const int j = j0 + rr;
                const float cand = tanhf(cs[wv][rr][b] + cbv[rr]);
                const float z    = zs[wv][rr][b];
                const float hold = hsrc[b * DIM + j];   // fp32 state
                const float hn   = z * hold + (1.f - z) * cand;
                hdst[b * DIM + j] = hn;
                if (g == NGROUP - 1)
                    ysf[((size_t)b * SEQ + t) * DIM + j] = hn;
            }
        }
        // bar2: h(t) published (prod[g] = t+1)
        gbar_grp(bar, g, bkg, ep, dead, prodp, (unsigned)(t + 1));
    }

    if (dead && tid == 0)
        ysf[blockIdx.x] = 1.0e8f;   // unmistakable failure sentinel
}

// ---------------------------------------------------------------------------
// Logits GEMM (unchanged): C[m][n] = sum_k ys[m][k] * outW[n][k]
// ---------------------------------------------------------------------------
#define BM 128
#define BN 128
#define BK 64

__global__ void __launch_bounds__(256) out_gemm(
    const float* __restrict__ A,   // [4096][1024]  fp32
    const float* __restrict__ B,   // [32000][1024] fp32
    float* __restrict__ C)         // [4096][32000]
{
    __shared__ __hip_bfloat16 At[BM][BK + 8];
    __shared__ __hip_bfloat16 Bt[BN][BK + 8];

    const int tid  = threadIdx.x;
    const int lane = tid & 63;
    const int wv   = tid >> 6;
    const int wm   = wv >> 1, wn = wv & 1;
    const int m0   = blockIdx.y * BM;
    const int n0   = blockIdx.x * BN;

    f32x4 acc[4][4];
    #pragma unroll
    for (int i = 0; i < 4; ++i)
        #pragma unroll
        for (int jj = 0; jj < 4; ++jj)
            acc[i][jj] = (f32x4){0.f, 0.f, 0.f, 0.f};

    const int srow = tid >> 3;           // 0..31
    const int scol = (tid & 7) * 8;      // 0..56
    const int l15  = lane & 15;
    const int l4   = lane >> 4;

    for (int kt = 0; kt < DIM / BK; ++kt) {
        const int k0 = kt * BK;
        #pragma unroll
        for (int rnd = 0; rnd < 4; ++rnd) {
            const int row = rnd * 32 + srow;
            *(u16x8*)&At[row][scol] =
                cvt8_bf16(&A[(size_t)(m0 + row) * DIM + k0 + scol]);
            *(u16x8*)&Bt[row][scol] =
                cvt8_bf16(&B[(size_t)(n0 + row) * DIM + k0 + scol]);
        }
        __syncthreads();
        #pragma unroll
        for (int ks = 0; ks < 2; ++ks) {
            bf16x8 av[4], bv[4];
            #pragma unroll
            for (int i = 0; i < 4; ++i) {
                av[i] = *(const bf16x8*)&At[wm * 64 + i * 16 + l15][ks * 32 + l4 * 8];
                bv[i] = *(const bf16x8*)&Bt[wn * 64 + i * 16 + l15][ks * 32 + l4 * 8];
            }
            #pragma unroll
            for (int i = 0; i < 4; ++i)
                #pragma unroll
                for (int jj = 0; jj < 4; ++jj)
                    acc[i][jj] = __builtin_amdgcn_mfma_f32_16x16x32_bf16(
                        av[i], bv[jj], acc[i][jj], 0, 0, 0);
        }
        __syncthreads();
    }

    const int rq = l4 * 4;
    #pragma unroll
    for (int i = 0; i < 4; ++i) {
        const int rbase = m0 + wm * 64 + i * 16 + rq;
        #pragma unroll
        for (int jj = 0; jj < 4; ++jj) {
            const int col = n0 + wn * 64 + jj * 16 + l15;
            #pragma unroll
            for (int r2 = 0; r2 < 4; ++r2)
                C[(size_t)(rbase + r2) * VOCAB + col] = acc[i][jj][r2];
        }
    }
}

// ---------------------------------------------------------------------------
extern "C" void kernel_launch(void* const* d_in, const int* in_sizes, int n_in,
                              void* d_out, int out_size, void* d_ws, size_t ws_size,
                              hipStream_t stream)
{
    (void)in_sizes; (void)n_in; (void)out_size; (void)ws_size;
    const int*   ids  = (const int*)  d_in[0];
    const float* embW = (const float*)d_in[1];
    const float* hst  = (const float*)d_in[2];
    const float* gW   = (const float*)d_in[3];
    const float* gB   = (const float*)d_in[4];
    const float* cW   = (const float*)d_in[5];
    const float* cB   = (const float*)d_in[6];
    const float* outW = (const float*)d_in[7];
    float* logits = (float*)d_out;

    // workspace carve-up (~17.4 MiB)
    char* ws = (char*)d_ws;
    unsigned* bar  = (unsigned*)ws;                               // 8 KiB
    float*    rbuf = (float*)(ws + 8192);                         // 128 KiB
    float*    hbuf = (float*)(ws + 8192 + 131072);                // 512 KiB
    float*    ysf  = (float*)(ws + 8192 + 131072 + 524288);       // 16 MiB

    // 1) zero barrier/flag counters
    bar_init_kernel<<<dim3(1), dim3(1024), 0, stream>>>(bar);

    // 2) layer-pipelined persistent-weight GRU scan
    gru_scan<<<dim3(SCAN_BLOCKS), dim3(SCAN_THREADS), 0, stream>>>(
        ids, embW, hst, gW, gB, cW, cB, hbuf, rbuf, ysf, bar);

    // 3) logits GEMM
    out_gemm<<<dim3(VOCAB / BN, (NB * SEQ) / BM), dim3(256), 0, stream>>>(ysf, outW, logits);
}

// Round 9
// 19403.714 us; speedup vs baseline: 4.0222x; 1.1338x over previous
//
#include <hip/hip_runtime.h>
#include <hip/hip_bf16.h>

#define VOCAB  32000
#define DIM    1024
#define NLAYER 4
#define NB     8
#define SEQ    512

#define NGROUP       4
#define GBLKS        64                    // blocks per layer-group
#define SCAN_BLOCKS  (NGROUP * GBLKS)      // 256
#define SCAN_THREADS 512                   // 8 waves; wave owns 2 full rows

typedef __attribute__((ext_vector_type(8))) short          bf16x8;
typedef __attribute__((ext_vector_type(4))) float          f32x4;
typedef __attribute__((ext_vector_type(8))) unsigned short u16x8;
typedef __attribute__((ext_vector_type(2))) _Float16       h2f;
typedef __attribute__((ext_vector_type(4))) _Float16       h4f;

__device__ __forceinline__ void bfly(float& v) {
    #pragma unroll
    for (int off = 32; off > 0; off >>= 1) v += __shfl_xor(v, off);
}

__device__ __forceinline__ u16x8 cvt8_bf16(const float* p) {
    float4 f0 = *(const float4*)p;
    float4 f1 = *(const float4*)(p + 4);
    union { __hip_bfloat16 h[8]; u16x8 v; } u;
    u.h[0] = __float2bfloat16(f0.x); u.h[1] = __float2bfloat16(f0.y);
    u.h[2] = __float2bfloat16(f0.z); u.h[3] = __float2bfloat16(f0.w);
    u.h[4] = __float2bfloat16(f1.x); u.h[5] = __float2bfloat16(f1.y);
    u.h[6] = __float2bfloat16(f1.z); u.h[7] = __float2bfloat16(f1.w);
    return u.v;
}

// ---------------------------------------------------------------------------
__global__ void bar_init_kernel(unsigned* __restrict__ bar) {
    bar[threadIdx.x]        = 0u;
    bar[threadIdx.x + 1024] = 0u;   // 2048 words
}

// ---------------------------------------------------------------------------
// RMW-free slot barrier for one 64-block group.
// Arrival: block bkg's tid0 release-STORES seq into its own slot (64 parallel
// stores, no atomic RMW serialization). Detection: wave 0 polls all 64 slots
// (relaxed agent loads = coherence-point reads) + __all ballot; then ONE
// acquire fence (cache inv) per block per barrier. Monotonic seq per call.
// ---------------------------------------------------------------------------
__device__ __forceinline__ void slot_bar(unsigned* __restrict__ slots, int bkg,
                                         unsigned seq, bool& dead) {
    __syncthreads();   // every wave's stores drained (per-wave vmcnt -> L2)
    const int tid = threadIdx.x;
    if (tid == 0)
        __hip_atomic_store(&slots[bkg], seq, __ATOMIC_RELEASE,
                           __HIP_MEMORY_SCOPE_AGENT);
    if (tid < 64 && !dead) {
        unsigned guard = 0;
        for (;;) {
            unsigned v = __hip_atomic_load(&slots[tid], __ATOMIC_RELAXED,
                                           __HIP_MEMORY_SCOPE_AGENT);
            if (__all((int)(v >= seq))) break;
            __builtin_amdgcn_s_sleep(1);
            if (++guard > (1u << 16)) { dead = true; break; }
        }
        __builtin_amdgcn_fence(__ATOMIC_ACQUIRE, "agent");
    }
    __syncthreads();
}

// ---------------------------------------------------------------------------
// Layer-pipelined persistent-weight GRU scan (round-8 compute, slot barriers).
// Group g = blockIdx>>6 owns layer g; wave wv owns rows j0=bkg*16+wv*2, j0+1
// fully (96 pinned fp16-h2 VGPRs of weights). h ring 4 deep.
// Gates before staging:  xin ready   <=> slots2[g-1][*] >= t+2
//                        ring slot free <=> slots1[g+1][*] >= t-3  (t>=4)
// bar1 (slots1, seq t+1): r published / xin consumed.
// bar2 (slots2, seq t+2): h(t) published.
// ---------------------------------------------------------------------------
__global__ void __launch_bounds__(SCAN_THREADS)
__attribute__((amdgpu_waves_per_eu(2, 2)))
gru_scan(
    const int*   __restrict__ ids,     // [NB][SEQ]
    const float* __restrict__ embW,    // [VOCAB][DIM]
    const float* __restrict__ hstart,  // [NLAYER][DIM]
    const float* __restrict__ gW,      // [NLAYER][2*DIM][2*DIM]
    const float* __restrict__ gB,      // [NLAYER][2*DIM]
    const float* __restrict__ cW,      // [NLAYER][DIM][2*DIM]
    const float* __restrict__ cB,      // [NLAYER][DIM]
    float* __restrict__ hbuf,          // [4][NLAYER][NB][DIM]
    float* __restrict__ rbuf,          // [NGROUP][NB][DIM]
    float* __restrict__ ysf,           // [NB][SEQ][DIM] fp32
    unsigned* __restrict__ bar)
{
    __shared__ _Float16 lxh[NB][DIM];   // 16KB: xin (A) / rh (B)
    __shared__ _Float16 lhh[NB][DIM];   // 16KB: own h_old (dot input)
    __shared__ float rs[8][2][NB];
    __shared__ float zs[8][2][NB];
    __shared__ float cs[8][2][NB];

    const int tid  = threadIdx.x;
    const int lane = tid & 63;
    const int wv   = tid >> 6;               // 0..7
    const int g    = blockIdx.x >> 6;        // layer group 0..3
    const int bkg  = blockIdx.x & (GBLKS-1); // 0..63
    const int j0   = bkg * 16 + wv * 2;      // wave's first row

    // ---- persistent fp16 weights: [row][type z,r,c][16 h2] ----
    h2f W[2][3][16];
    float bzv[2], brv[2], cbv[2];
    #pragma unroll
    for (int rr = 0; rr < 2; ++rr) {
        const int j = j0 + rr;
        const float* wz = gW + ((size_t)g * 2048 + j) * 2048;
        const float* wr = gW + ((size_t)g * 2048 + 1024 + j) * 2048;
        const float* wc = cW + ((size_t)g * 1024 + j) * 2048;
        #pragma unroll
        for (int it = 0; it < 4; ++it) {
            const int k0 = it * 256 + lane * 4;
            float4 f;
            f = *(const float4*)(wz + k0);
            W[rr][0][2*it]     = h2f{(_Float16)f.x, (_Float16)f.y};
            W[rr][0][2*it+1]   = h2f{(_Float16)f.z, (_Float16)f.w};
            f = *(const float4*)(wz + 1024 + k0);
            W[rr][0][8+2*it]   = h2f{(_Float16)f.x, (_Float16)f.y};
            W[rr][0][9+2*it]   = h2f{(_Float16)f.z, (_Float16)f.w};
            f = *(const float4*)(wr + k0);
            W[rr][1][2*it]     = h2f{(_Float16)f.x, (_Float16)f.y};
            W[rr][1][2*it+1]   = h2f{(_Float16)f.z, (_Float16)f.w};
            f = *(const float4*)(wr + 1024 + k0);
            W[rr][1][8+2*it]   = h2f{(_Float16)f.x, (_Float16)f.y};
            W[rr][1][9+2*it]   = h2f{(_Float16)f.z, (_Float16)f.w};
            f = *(const float4*)(wc + k0);
            W[rr][2][2*it]     = h2f{(_Float16)f.x, (_Float16)f.y};
            W[rr][2][2*it+1]   = h2f{(_Float16)f.z, (_Float16)f.w};
            f = *(const float4*)(wc + 1024 + k0);
            W[rr][2][8+2*it]   = h2f{(_Float16)f.x, (_Float16)f.y};
            W[rr][2][9+2*it]   = h2f{(_Float16)f.z, (_Float16)f.w};
        }
        bzv[rr] = gB[g * 2048 + j];
        brv[rr] = gB[g * 2048 + 1024 + j];
        cbv[rr] = cB[g * DIM + j];
    }
    #pragma unroll
    for (int rr = 0; rr < 2; ++rr)
        #pragma unroll
        for (int ty = 0; ty < 3; ++ty)
            #pragma unroll
            for (int i = 0; i < 16; ++i)
                asm volatile("" : "+v"(W[rr][ty][i]));   // pin: no remat/spill

    bool dead = false;

    unsigned* slots1g = bar + g * 64;
    unsigned* slots2g = bar + 256 + g * 64;
    unsigned* s2prev  = (g > 0)          ? bar + 256 + (g - 1) * 64 : nullptr;
    unsigned* s1next  = (g < NGROUP - 1) ? bar + (g + 1) * 64       : nullptr;

    float* rbufg = rbuf + (size_t)g * NB * DIM;

    // init own layer h(-1) into ring slot 3
    if (tid < 128) {
        int e = bkg * 128 + tid;   // 0..8191
        hbuf[((size_t)3 * NLAYER + g) * NB * DIM + e] = hstart[g * DIM + (e & (DIM - 1))];
    }
    slot_bar(slots2g, bkg, 1u, dead);

    for (int t = 0; t < SEQ; ++t) {
        const int so = (t + 3) & 3;   // h_old slot
        const int sw = t & 3;         // h_new slot
        const float* hsrc = hbuf + ((size_t)so * NLAYER + g) * NB * DIM;
        float*       hdst = hbuf + ((size_t)sw * NLAYER + g) * NB * DIM;

        // ---- peer gates: producer (xin ready) + backpressure (slot free) ----
        {
            const unsigned need_a = (g > 0) ? (unsigned)(t + 2) : 0u;
            const unsigned need_b = (g < NGROUP - 1 && t >= 4) ? (unsigned)(t - 3) : 0u;
            if (tid < 64 && !dead && (need_a | need_b)) {
                unsigned guard = 0;
                for (;;) {
                    bool ok = true;
                    if (need_a)
                        ok &= (__hip_atomic_load(&s2prev[tid], __ATOMIC_RELAXED,
                                                 __HIP_MEMORY_SCOPE_AGENT) >= need_a);
                    if (need_b)
                        ok &= (__hip_atomic_load(&s1next[tid], __ATOMIC_RELAXED,
                                                 __HIP_MEMORY_SCOPE_AGENT) >= need_b);
                    if (__all((int)ok)) break;
                    __builtin_amdgcn_s_sleep(1);
                    if (++guard > (1u << 16)) { dead = true; break; }
                }
                __builtin_amdgcn_fence(__ATOMIC_ACQUIRE, "agent");
            }
            __syncthreads();
        }

        // ---- stage xin -> lxh, h_old -> lhh (fp16) ----
        if (g == 0) {
            #pragma unroll
            for (int q = 0; q < 4; ++q) {
                int e = q * SCAN_THREADS + tid;   // 0..2047 h4f units
                int b = e >> 8;
                int row = ids[b * SEQ + t];
                float4 f = ((const float4*)(embW + (size_t)row * DIM))[e & 255];
                ((h4f*)&lxh[0][0])[e] =
                    h4f{(_Float16)f.x, (_Float16)f.y, (_Float16)f.z, (_Float16)f.w};
            }
        } else {
            const float* src = hbuf + ((size_t)sw * NLAYER + (g - 1)) * NB * DIM;
            #pragma unroll
            for (int q = 0; q < 4; ++q) {
                int e = q * SCAN_THREADS + tid;
                float4 f = ((const float4*)src)[e];
                ((h4f*)&lxh[0][0])[e] =
                    h4f{(_Float16)f.x, (_Float16)f.y, (_Float16)f.z, (_Float16)f.w};
            }
        }
        #pragma unroll
        for (int q = 0; q < 4; ++q) {
            int e = q * SCAN_THREADS + tid;
            float4 f = ((const float4*)hsrc)[e];
            ((h4f*)&lhh[0][0])[e] =
                h4f{(_Float16)f.x, (_Float16)f.y, (_Float16)f.z, (_Float16)f.w};
        }
        __syncthreads();

        // ---- Phase A: full z, r, candA dots for 2 rows x 8 batches ----
        float az[2][NB], ar[2][NB], ac[2][NB];
        #pragma unroll
        for (int rr = 0; rr < 2; ++rr)
            #pragma unroll
            for (int b = 0; b < NB; ++b) { az[rr][b] = 0.f; ar[rr][b] = 0.f; ac[rr][b] = 0.f; }

        #pragma unroll
        for (int it = 0; it < 4; ++it) {
            const int k0 = it * 256 + lane * 4;
            #pragma unroll
            for (int b = 0; b < NB; ++b) {
                h4f xv = *(const h4f*)&lxh[b][k0];
                h4f hv = *(const h4f*)&lhh[b][k0];
                h2f x01{xv[0], xv[1]}, x23{xv[2], xv[3]};
                h2f h01{hv[0], hv[1]}, h23{hv[2], hv[3]};
                #pragma unroll
                for (int rr = 0; rr < 2; ++rr) {
                    az[rr][b] = __builtin_amdgcn_fdot2(W[rr][0][2*it],   x01, az[rr][b], false);
                    az[rr][b] = __builtin_amdgcn_fdot2(W[rr][0][2*it+1], x23, az[rr][b], false);
                    az[rr][b] = __builtin_amdgcn_fdot2(W[rr][0][8+2*it], h01, az[rr][b], false);
                    az[rr][b] = __builtin_amdgcn_fdot2(W[rr][0][9+2*it], h23, az[rr][b], false);
                    ar[rr][b] = __builtin_amdgcn_fdot2(W[rr][1][2*it],   x01, ar[rr][b], false);
                    ar[rr][b] = __builtin_amdgcn_fdot2(W[rr][1][2*it+1], x23, ar[rr][b], false);
                    ar[rr][b] = __builtin_amdgcn_fdot2(W[rr][1][8+2*it], h01, ar[rr][b], false);
                    ar[rr][b] = __builtin_amdgcn_fdot2(W[rr][1][9+2*it], h23, ar[rr][b], false);
                    ac[rr][b] = __builtin_amdgcn_fdot2(W[rr][2][2*it],   x01, ac[rr][b], false);
                    ac[rr][b] = __builtin_amdgcn_fdot2(W[rr][2][2*it+1], x23, ac[rr][b], false);
                }
            }
        }
        #pragma unroll
        for (int rr = 0; rr < 2; ++rr)
            #pragma unroll
            for (int b = 0; b < NB; ++b) { bfly(az[rr][b]); bfly(ar[rr][b]); bfly(ac[rr][b]); }

        if (lane == 0) {
            #pragma unroll
            for (int rr = 0; rr < 2; ++rr)
                #pragma unroll
                for (int b = 0; b < NB; ++b) {
                    zs[wv][rr][b] = 1.f / (1.f + expf(-(az[rr][b] + bzv[rr])));
                    rs[wv][rr][b] = 1.f / (1.f + expf(-(ar[rr][b] + brv[rr])));
                    cs[wv][rr][b] = ac[rr][b];
                }
        }
        if (lane < NB) {   // publish r (same-wave LDS RAW)
            rbufg[lane * DIM + j0]     = rs[wv][0][lane];
            rbufg[lane * DIM + j0 + 1] = rs[wv][1][lane];
        }
        // bar1: r published / xin consumed
        slot_bar(slots1g, bkg, (unsigned)(t + 1), dead);

        // ---- stage rh = r * h_old -> lxh ----
        #pragma unroll
        for (int q = 0; q < 4; ++q) {
            int e = q * SCAN_THREADS + tid;
            float4 r4 = ((const float4*)rbufg)[e];
            float4 h4 = ((const float4*)hsrc)[e];
            ((h4f*)&lxh[0][0])[e] = h4f{
                (_Float16)(r4.x * h4.x), (_Float16)(r4.y * h4.y),
                (_Float16)(r4.z * h4.z), (_Float16)(r4.w * h4.w)};
        }
        __syncthreads();

        // ---- Phase B: candB + state update ----
        float ab[2][NB];
        #pragma unroll
        for (int rr = 0; rr < 2; ++rr)
            #pragma unroll
            for (int b = 0; b < NB; ++b) ab[rr][b] = 0.f;
        #pragma unroll
        for (int it = 0; it < 4; ++it) {
            const int k0 = it * 256 + lane * 4;
            #pragma unroll
            for (int b = 0; b < NB; ++b) {
                h4f pv = *(const h4f*)&lxh[b][k0];
                h2f p01{pv[0], pv[1]}, p23{pv[2], pv[3]};
                #pragma unroll
                for (int rr = 0; rr < 2; ++rr) {
                    ab[rr][b] = __builtin_amdgcn_fdot2(W[rr][2][8+2*it], p01, ab[rr][b], false);
                    ab[rr][b] = __builtin_amdgcn_fdot2(W[rr][2][9+2*it], p23, ab[rr][b], false);
                }
            }
        }
        #pragma unroll
        for (int rr = 0; rr < 2; ++rr)
            #pragma unroll
            for (int b = 0; b < NB; ++b) bfly(ab[rr][b]);

        if (lane == 0) {
            #pragma unroll
            for (int rr = 0; rr < 2; ++rr)
                #pragma unroll
                for (int b = 0; b < NB; ++b) cs[wv][rr][b] += ab[rr][b];
        }
        if (lane < NB) {   // same-wave LDS RAW after lane-0 writes
            const int b = lane;
            #pragma unroll
            for (int rr = 0; rr < 2; ++rr) {
                const int j = j0 + rr;
                const float cand = tanhf(cs[wv][rr][b] + cbv[rr]);
                const float z    = zs[wv][rr][b];
                const float hold = hsrc[b * DIM + j];   // fp32 state
                const float hn   = z * hold + (1.f - z) * cand;
                hdst[b * DIM + j] = hn;
                if (g == NGROUP - 1)
                    ysf[((size_t)b * SEQ + t) * DIM + j] = hn;
            }
        }
        // bar2: h(t) published
        slot_bar(slots2g, bkg, (unsigned)(t + 2), dead);
    }

    if (dead && tid == 0)
        ysf[blockIdx.x] = 1.0e8f;   // unmistakable failure sentinel
}

// ---------------------------------------------------------------------------
// Logits GEMM (unchanged): C[m][n] = sum_k ys[m][k] * outW[n][k]
// ---------------------------------------------------------------------------
#define BM 128
#define BN 128
#define BK 64

__global__ void __launch_bounds__(256) out_gemm(
    const float* __restrict__ A,   // [4096][1024]  fp32
    const float* __restrict__ B,   // [32000][1024] fp32
    float* __restrict__ C)         // [4096][32000]
{
    __shared__ __hip_bfloat16 At[BM][BK + 8];
    __shared__ __hip_bfloat16 Bt[BN][BK + 8];

    const int tid  = threadIdx.x;
    const int lane = tid & 63;
    const int wv   = tid >> 6;
    const int wm   = wv >> 1, wn = wv & 1;
    const int m0   = blockIdx.y * BM;
    const int n0   = blockIdx.x * BN;

    f32x4 acc[4][4];
    #pragma unroll
    for (int i = 0; i < 4; ++i)
        #pragma unroll
        for (int jj = 0; jj < 4; ++jj)
            acc[i][jj] = (f32x4){0.f, 0.f, 0.f, 0.f};

    const int srow = tid >> 3;           // 0..31
    const int scol = (tid & 7) * 8;      // 0..56
    const int l15  = lane & 15;
    const int l4   = lane >> 4;

    for (int kt = 0; kt < DIM / BK; ++kt) {
        const int k0 = kt * BK;
        #pragma unroll
        for (int rnd = 0; rnd < 4; ++rnd) {
            const int row = rnd * 32 + srow;
            *(u16x8*)&At[row][scol] =
                cvt8_bf16(&A[(size_t)(m0 + row) * DIM + k0 + scol]);
            *(u16x8*)&Bt[row][scol] =
                cvt8_bf16(&B[(size_t)(n0 + row) * DIM + k0 + scol]);
        }
        __syncthreads();
        #pragma unroll
        for (int ks = 0; ks < 2; ++ks) {
            bf16x8 av[4], bv[4];
            #pragma unroll
            for (int i = 0; i < 4; ++i) {
                av[i] = *(const bf16x8*)&At[wm * 64 + i * 16 + l15][ks * 32 + l4 * 8];
                bv[i] = *(const bf16x8*)&Bt[wn * 64 + i * 16 + l15][ks * 32 + l4 * 8];
            }
            #pragma unroll
            for (int i = 0; i < 4; ++i)
                #pragma unroll
                for (int jj = 0; jj < 4; ++jj)
                    acc[i][jj] = __builtin_amdgcn_mfma_f32_16x16x32_bf16(
                        av[i], bv[jj], acc[i][jj], 0, 0, 0);
        }
        __syncthreads();
    }

    const int rq = l4 * 4;
    #pragma unroll
    for (int i = 0; i < 4; ++i) {
        const int rbase = m0 + wm * 64 + i * 16 + rq;
        #pragma unroll
        for (int jj = 0; jj < 4; ++jj) {
            const int col = n0 + wn * 64 + jj * 16 + l15;
            #pragma unroll
            for (int r2 = 0; r2 < 4; ++r2)
                C[(size_t)(rbase + r2) * VOCAB + col] = acc[i][jj][r2];
        }
    }
}

// ---------------------------------------------------------------------------
extern "C" void kernel_launch(void* const* d_in, const int* in_sizes, int n_in,
                              void* d_out, int out_size, void* d_ws, size_t ws_size,
                              hipStream_t stream)
{
    (void)in_sizes; (void)n_in; (void)out_size; (void)ws_size;
    const int*   ids  = (const int*)  d_in[0];
    const float* embW = (const float*)d_in[1];
    const float* hst  = (const float*)d_in[2];
    const float* gW   = (const float*)d_in[3];
    const float* gB   = (const float*)d_in[4];
    const float* cW   = (const float*)d_in[5];
    const float* cB   = (const float*)d_in[6];
    const float* outW = (const float*)d_in[7];
    float* logits = (float*)d_out;

    // workspace carve-up (~17.4 MiB)
    char* ws = (char*)d_ws;
    unsigned* bar  = (unsigned*)ws;                               // 8 KiB
    float*    rbuf = (float*)(ws + 8192);                         // 128 KiB
    float*    hbuf = (float*)(ws + 8192 + 131072);                // 512 KiB
    float*    ysf  = (float*)(ws + 8192 + 131072 + 524288);       // 16 MiB

    // 1) zero slot arrays
    bar_init_kernel<<<dim3(1), dim3(1024), 0, stream>>>(bar);

    // 2) layer-pipelined persistent-weight GRU scan (slot barriers)
    gru_scan<<<dim3(SCAN_BLOCKS), dim3(SCAN_THREADS), 0, stream>>>(
        ids, embW, hst, gW, gB, cW, cB, hbuf, rbuf, ysf, bar);

    // 3) logits GEMM
    out_gemm<<<dim3(VOCAB / BN, (NB * SEQ) / BM), dim3(256), 0, stream>>>(ysf, outW, logits);
}

// Round 10
// 13581.688 us; speedup vs baseline: 5.7463x; 1.4287x over previous
//
#include <hip/hip_runtime.h>
#include <hip/hip_bf16.h>

#define VOCAB  32000
#define DIM    1024
#define NLAYER 4
#define NB     8
#define SEQ    512

#define NGROUP       4
#define GBLKS        64                    // blocks per layer-group
#define SCAN_BLOCKS  (NGROUP * GBLKS)      // 256
#define SCAN_THREADS 512                   // 8 waves; wave owns 2 full rows

typedef __attribute__((ext_vector_type(8))) short          bf16x8;
typedef __attribute__((ext_vector_type(4))) float          f32x4;
typedef __attribute__((ext_vector_type(8))) unsigned short u16x8;
typedef __attribute__((ext_vector_type(2))) _Float16       h2f;
typedef __attribute__((ext_vector_type(4))) _Float16       h4f;

__device__ __forceinline__ void bfly(float& v) {
    #pragma unroll
    for (int off = 32; off > 0; off >>= 1) v += __shfl_xor(v, off);
}

__device__ __forceinline__ u16x8 cvt8_bf16(const float* p) {
    float4 f0 = *(const float4*)p;
    float4 f1 = *(const float4*)(p + 4);
    union { __hip_bfloat16 h[8]; u16x8 v; } u;
    u.h[0] = __float2bfloat16(f0.x); u.h[1] = __float2bfloat16(f0.y);
    u.h[2] = __float2bfloat16(f0.z); u.h[3] = __float2bfloat16(f0.w);
    u.h[4] = __float2bfloat16(f1.x); u.h[5] = __float2bfloat16(f1.y);
    u.h[6] = __float2bfloat16(f1.z); u.h[7] = __float2bfloat16(f1.w);
    return u.v;
}

// ---- coherence-point (L3) loads/stores: bypass per-XCD L2, so no cache
//      fences are needed anywhere in the pipeline hot path ----
__device__ __forceinline__ void ld4v(f32x4& d, const float* p) {
    asm volatile("global_load_dwordx4 %0, %1, off sc0 sc1"
                 : "=&v"(d) : "v"(p));
}
__device__ __forceinline__ void st1v(float* p, float v) {
    asm volatile("global_store_dword %0, %1, off sc0 sc1"
                 :: "v"(p), "v"(v) : "memory");
}
__device__ __forceinline__ void vmwait0() {
    asm volatile("s_waitcnt vmcnt(0)" ::: "memory");
}

// ---------------------------------------------------------------------------
// bar layout (unsigned words): slots1[g] at g*512, slots2[g] at 2048+g*512;
// slot i of an array at offset i*8 (32 B apart to spread L3 sectors).
// ---------------------------------------------------------------------------
__global__ void bar_init_kernel(unsigned* __restrict__ bar) {
    bar[threadIdx.x]        = 0u;
    bar[threadIdx.x + 1024] = 0u;
    bar[threadIdx.x + 2048] = 0u;
    bar[threadIdx.x + 3072] = 0u;   // 4096 words = 16 KiB
}

// ---------------------------------------------------------------------------
// Fence-free slot barrier. __syncthreads drains every wave's vmcnt (compiler
// emits waitcnt before s_barrier), so all sc1 data stores are already AT the
// coherence point; arrival is a relaxed agent store, detection a relaxed
// 64-lane poll + __all. No wbl2 / no inv.
// ---------------------------------------------------------------------------
__device__ __forceinline__ void slot_bar(unsigned* __restrict__ slots, int bkg,
                                         unsigned seq, bool& dead) {
    __syncthreads();
    const int tid = threadIdx.x;
    if (tid == 0)
        __hip_atomic_store(&slots[bkg * 8], seq, __ATOMIC_RELAXED,
                           __HIP_MEMORY_SCOPE_AGENT);
    if (tid < 64 && !dead) {
        unsigned guard = 0;
        for (;;) {
            unsigned v = __hip_atomic_load(&slots[tid * 8], __ATOMIC_RELAXED,
                                           __HIP_MEMORY_SCOPE_AGENT);
            if (__all((int)(v >= seq))) break;
            __builtin_amdgcn_s_sleep(1);
            if (++guard > (1u << 16)) { dead = true; break; }
        }
    }
    __syncthreads();
}

// ---------------------------------------------------------------------------
// Layer-pipelined persistent-weight GRU scan; fence-free sc1 communication.
// Group g = blockIdx>>6 owns layer g; wave wv owns rows j0=bkg*16+wv*2, j0+1
// (96 pinned fp16-h2 VGPRs of weights). h ring 4 deep, h/rbuf via sc1 ops.
// ---------------------------------------------------------------------------
__global__ void __launch_bounds__(SCAN_THREADS)
__attribute__((amdgpu_waves_per_eu(2, 2)))
gru_scan(
    const int*   __restrict__ ids,     // [NB][SEQ]
    const float* __restrict__ embW,    // [VOCAB][DIM]
    const float* __restrict__ hstart,  // [NLAYER][DIM]
    const float* __restrict__ gW,      // [NLAYER][2*DIM][2*DIM]
    const float* __restrict__ gB,      // [NLAYER][2*DIM]
    const float* __restrict__ cW,      // [NLAYER][DIM][2*DIM]
    const float* __restrict__ cB,      // [NLAYER][DIM]
    float* __restrict__ hbuf,          // [4][NLAYER][NB][DIM]
    float* __restrict__ rbuf,          // [NGROUP][NB][DIM]
    float* __restrict__ ysf,           // [NB][SEQ][DIM] fp32
    unsigned* __restrict__ bar)
{
    __shared__ _Float16 lxh[NB][DIM];   // 16KB: xin (A) / rh (B), fp16
    __shared__ _Float16 lhh[NB][DIM];   // 16KB: own h_old, fp16 (dot input)
    __shared__ float    lhf[NB][DIM];   // 32KB: own h_old, fp32 (rh pass)
    __shared__ float zs[8][2][NB];
    __shared__ float cs[8][2][NB];

    const int tid  = threadIdx.x;
    const int lane = tid & 63;
    const int wv   = tid >> 6;               // 0..7
    const int g    = blockIdx.x >> 6;        // layer group 0..3
    const int bkg  = blockIdx.x & (GBLKS-1); // 0..63
    const int j0   = bkg * 16 + wv * 2;      // wave's first row

    // ---- persistent fp16 weights: [row][type z,r,c][16 h2] ----
    h2f W[2][3][16];
    float bzv[2], brv[2], cbv[2];
    #pragma unroll
    for (int rr = 0; rr < 2; ++rr) {
        const int j = j0 + rr;
        const float* wz = gW + ((size_t)g * 2048 + j) * 2048;
        const float* wr = gW + ((size_t)g * 2048 + 1024 + j) * 2048;
        const float* wc = cW + ((size_t)g * 1024 + j) * 2048;
        #pragma unroll
        for (int it = 0; it < 4; ++it) {
            const int k0 = it * 256 + lane * 4;
            float4 f;
            f = *(const float4*)(wz + k0);
            W[rr][0][2*it]     = h2f{(_Float16)f.x, (_Float16)f.y};
            W[rr][0][2*it+1]   = h2f{(_Float16)f.z, (_Float16)f.w};
            f = *(const float4*)(wz + 1024 + k0);
            W[rr][0][8+2*it]   = h2f{(_Float16)f.x, (_Float16)f.y};
            W[rr][0][9+2*it]   = h2f{(_Float16)f.z, (_Float16)f.w};
            f = *(const float4*)(wr + k0);
            W[rr][1][2*it]     = h2f{(_Float16)f.x, (_Float16)f.y};
            W[rr][1][2*it+1]   = h2f{(_Float16)f.z, (_Float16)f.w};
            f = *(const float4*)(wr + 1024 + k0);
            W[rr][1][8+2*it]   = h2f{(_Float16)f.x, (_Float16)f.y};
            W[rr][1][9+2*it]   = h2f{(_Float16)f.z, (_Float16)f.w};
            f = *(const float4*)(wc + k0);
            W[rr][2][2*it]     = h2f{(_Float16)f.x, (_Float16)f.y};
            W[rr][2][2*it+1]   = h2f{(_Float16)f.z, (_Float16)f.w};
            f = *(const float4*)(wc + 1024 + k0);
            W[rr][2][8+2*it]   = h2f{(_Float16)f.x, (_Float16)f.y};
            W[rr][2][9+2*it]   = h2f{(_Float16)f.z, (_Float16)f.w};
        }
        bzv[rr] = gB[g * 2048 + j];
        brv[rr] = gB[g * 2048 + 1024 + j];
        cbv[rr] = cB[g * DIM + j];
    }
    #pragma unroll
    for (int rr = 0; rr < 2; ++rr)
        #pragma unroll
        for (int ty = 0; ty < 3; ++ty)
            #pragma unroll
            for (int i = 0; i < 16; ++i)
                asm volatile("" : "+v"(W[rr][ty][i]));   // pin: no remat/spill

    bool dead = false;

    unsigned* slots1g = bar + g * 512;
    unsigned* slots2g = bar + 2048 + g * 512;
    unsigned* s2prev  = (g > 0)          ? bar + 2048 + (g - 1) * 512 : nullptr;
    unsigned* s1next  = (g < NGROUP - 1) ? bar + (g + 1) * 512        : nullptr;

    float* rbufg = rbuf + (size_t)g * NB * DIM;

    // lane-local copy of own rows' h(t-1): batch = lane (lanes 0..7)
    float hkeep[2] = { hstart[g * DIM + j0], hstart[g * DIM + j0 + 1] };

    // init own layer h(-1) into ring slot 3 (sc1 stores -> L3)
    if (tid < 128) {
        int e = bkg * 128 + tid;   // 0..8191
        st1v(&hbuf[((size_t)3 * NLAYER + g) * NB * DIM + e],
             hstart[g * DIM + (e & (DIM - 1))]);
    }
    slot_bar(slots2g, bkg, 1u, dead);

    for (int t = 0; t < SEQ; ++t) {
        const int so = (t + 3) & 3;   // h_old slot
        const int sw = t & 3;         // h_new slot
        const float* hsrc = hbuf + ((size_t)so * NLAYER + g) * NB * DIM;
        float*       hdst = hbuf + ((size_t)sw * NLAYER + g) * NB * DIM;

        // ---- peer gates (fence-free: data arrives via sc1 loads) ----
        {
            const unsigned need_a = (g > 0) ? (unsigned)(t + 2) : 0u;
            const unsigned need_b = (g < NGROUP - 1 && t >= 4) ? (unsigned)(t - 3) : 0u;
            if (tid < 64 && !dead && (need_a | need_b)) {
                unsigned guard = 0;
                for (;;) {
                    bool ok = true;
                    if (need_a)
                        ok &= (__hip_atomic_load(&s2prev[tid * 8], __ATOMIC_RELAXED,
                                                 __HIP_MEMORY_SCOPE_AGENT) >= need_a);
                    if (need_b)
                        ok &= (__hip_atomic_load(&s1next[tid * 8], __ATOMIC_RELAXED,
                                                 __HIP_MEMORY_SCOPE_AGENT) >= need_b);
                    if (__all((int)ok)) break;
                    __builtin_amdgcn_s_sleep(1);
                    if (++guard > (1u << 16)) { dead = true; break; }
                }
            }
            __syncthreads();
        }

        // ---- stage xin -> lxh, h_old -> lhh(fp16)+lhf(fp32), via sc1 loads ----
        {
            f32x4 xv[4], hv[4];
            if (g == 0) {
                #pragma unroll
                for (int q = 0; q < 4; ++q) {
                    int e = q * SCAN_THREADS + tid;
                    int row = ids[(e >> 8) * SEQ + t];
                    xv[q] = ((const f32x4*)(embW + (size_t)row * DIM))[e & 255];
                }
            } else {
                const float* src = hbuf + ((size_t)sw * NLAYER + (g - 1)) * NB * DIM;
                #pragma unroll
                for (int q = 0; q < 4; ++q)
                    ld4v(xv[q], src + (size_t)(q * SCAN_THREADS + tid) * 4);
            }
            #pragma unroll
            for (int q = 0; q < 4; ++q)
                ld4v(hv[q], hsrc + (size_t)(q * SCAN_THREADS + tid) * 4);
            vmwait0();
            asm volatile("" : "+v"(xv[0]), "+v"(xv[1]), "+v"(xv[2]), "+v"(xv[3]),
                             "+v"(hv[0]), "+v"(hv[1]), "+v"(hv[2]), "+v"(hv[3]));
            #pragma unroll
            for (int q = 0; q < 4; ++q) {
                int e = q * SCAN_THREADS + tid;
                ((h4f*)&lxh[0][0])[e] = h4f{(_Float16)xv[q][0], (_Float16)xv[q][1],
                                            (_Float16)xv[q][2], (_Float16)xv[q][3]};
                ((h4f*)&lhh[0][0])[e] = h4f{(_Float16)hv[q][0], (_Float16)hv[q][1],
                                            (_Float16)hv[q][2], (_Float16)hv[q][3]};
                ((f32x4*)&lhf[0][0])[e] = hv[q];
            }
        }
        __syncthreads();

        // ---- Phase A: full z, r, candA dots for 2 rows x 8 batches ----
        float az[2][NB], ar[2][NB], ac[2][NB];
        #pragma unroll
        for (int rr = 0; rr < 2; ++rr)
            #pragma unroll
            for (int b = 0; b < NB; ++b) { az[rr][b] = 0.f; ar[rr][b] = 0.f; ac[rr][b] = 0.f; }

        #pragma unroll
        for (int it = 0; it < 4; ++it) {
            const int k0 = it * 256 + lane * 4;
            #pragma unroll
            for (int b = 0; b < NB; ++b) {
                h4f xv = *(const h4f*)&lxh[b][k0];
                h4f hv = *(const h4f*)&lhh[b][k0];
                h2f x01{xv[0], xv[1]}, x23{xv[2], xv[3]};
                h2f h01{hv[0], hv[1]}, h23{hv[2], hv[3]};
                #pragma unroll
                for (int rr = 0; rr < 2; ++rr) {
                    az[rr][b] = __builtin_amdgcn_fdot2(W[rr][0][2*it],   x01, az[rr][b], false);
                    az[rr][b] = __builtin_amdgcn_fdot2(W[rr][0][2*it+1], x23, az[rr][b], false);
                    az[rr][b] = __builtin_amdgcn_fdot2(W[rr][0][8+2*it], h01, az[rr][b], false);
                    az[rr][b] = __builtin_amdgcn_fdot2(W[rr][0][9+2*it], h23, az[rr][b], false);
                    ar[rr][b] = __builtin_amdgcn_fdot2(W[rr][1][2*it],   x01, ar[rr][b], false);
                    ar[rr][b] = __builtin_amdgcn_fdot2(W[rr][1][2*it+1], x23, ar[rr][b], false);
                    ar[rr][b] = __builtin_amdgcn_fdot2(W[rr][1][8+2*it], h01, ar[rr][b], false);
                    ar[rr][b] = __builtin_amdgcn_fdot2(W[rr][1][9+2*it], h23, ar[rr][b], false);
                    ac[rr][b] = __builtin_amdgcn_fdot2(W[rr][2][2*it],   x01, ac[rr][b], false);
                    ac[rr][b] = __builtin_amdgcn_fdot2(W[rr][2][2*it+1], x23, ac[rr][b], false);
                }
            }
        }
        #pragma unroll
        for (int rr = 0; rr < 2; ++rr)
            #pragma unroll
            for (int b = 0; b < NB; ++b) { bfly(az[rr][b]); bfly(ar[rr][b]); bfly(ac[rr][b]); }

        if (lane == 0) {
            #pragma unroll
            for (int rr = 0; rr < 2; ++rr)
                #pragma unroll
                for (int b = 0; b < NB; ++b) {
                    zs[wv][rr][b] = 1.f / (1.f + expf(-(az[rr][b] + bzv[rr])));
                    cs[wv][rr][b] = ac[rr][b];
                    st1v(rbufg + b * DIM + j0 + rr,
                         1.f / (1.f + expf(-(ar[rr][b] + brv[rr]))));
                }
        }
        // bar1: r published / xin consumed
        slot_bar(slots1g, bkg, (unsigned)(t + 1), dead);

        // ---- stage rh = r * h_old -> lxh (r via sc1, h from LDS fp32) ----
        {
            f32x4 rv[4];
            #pragma unroll
            for (int q = 0; q < 4; ++q)
                ld4v(rv[q], rbufg + (size_t)(q * SCAN_THREADS + tid) * 4);
            vmwait0();
            asm volatile("" : "+v"(rv[0]), "+v"(rv[1]), "+v"(rv[2]), "+v"(rv[3]));
            #pragma unroll
            for (int q = 0; q < 4; ++q) {
                int e = q * SCAN_THREADS + tid;
                f32x4 h4 = ((const f32x4*)&lhf[0][0])[e];
                ((h4f*)&lxh[0][0])[e] = h4f{
                    (_Float16)(rv[q][0] * h4[0]), (_Float16)(rv[q][1] * h4[1]),
                    (_Float16)(rv[q][2] * h4[2]), (_Float16)(rv[q][3] * h4[3])};
            }
        }
        __syncthreads();

        // ---- Phase B: candB + state update ----
        float ab[2][NB];
        #pragma unroll
        for (int rr = 0; rr < 2; ++rr)
            #pragma unroll
            for (int b = 0; b < NB; ++b) ab[rr][b] = 0.f;
        #pragma unroll
        for (int it = 0; it < 4; ++it) {
            const int k0 = it * 256 + lane * 4;
            #pragma unroll
            for (int b = 0; b < NB; ++b) {
                h4f pv = *(const h4f*)&lxh[b][k0];
                h2f p01{pv[0], pv[1]}, p23{pv[2], pv[3]};
                #pragma unroll
                for (int rr = 0; rr < 2; ++rr) {
                    ab[rr][b] = __builtin_amdgcn_fdot2(W[rr][2][8+2*it], p01, ab[rr][b], false);
                    ab[rr][b] = __builtin_amdgcn_fdot2(W[rr][2][9+2*it], p23, ab[rr][b], false);
                }
            }
        }
        #pragma unroll
        for (int rr = 0; rr < 2; ++rr)
            #pragma unroll
            for (int b = 0; b < NB; ++b) bfly(ab[rr][b]);

        if (lane == 0) {
            #pragma unroll
            for (int rr = 0; rr < 2; ++rr)
                #pragma unroll
                for (int b = 0; b < NB; ++b) cs[wv][rr][b] += ab[rr][b];
        }
        if (lane < NB) {   // same-wave LDS RAW after lane-0 writes
            const int b = lane;
            #pragma unroll
            for (int rr = 0; rr < 2; ++rr) {
                const int j = j0 + rr;
                const float cand = tanhf(cs[wv][rr][b] + cbv[rr]);
                const float z    = zs[wv][rr][b];
                const float hn   = z * hkeep[rr] + (1.f - z) * cand;
                hkeep[rr] = hn;
                st1v(hdst + b * DIM + j, hn);          // sc1 -> L3
                if (g == NGROUP - 1)
                    ysf[((size_t)b * SEQ + t) * DIM + j] = hn;  // cached; kernel-end flush
            }
        }
        // bar2: h(t) published
        slot_bar(slots2g, bkg, (unsigned)(t + 2), dead);
    }

    if (dead && tid == 0)
        ysf[blockIdx.x] = 1.0e8f;   // unmistakable failure sentinel
}

// ---------------------------------------------------------------------------
// Logits GEMM (unchanged): C[m][n] = sum_k ys[m][k] * outW[n][k]
// ---------------------------------------------------------------------------
#define BM 128
#define BN 128
#define BK 64

__global__ void __launch_bounds__(256) out_gemm(
    const float* __restrict__ A,   // [4096][1024]  fp32
    const float* __restrict__ B,   // [32000][1024] fp32
    float* __restrict__ C)         // [4096][32000]
{
    __shared__ __hip_bfloat16 At[BM][BK + 8];
    __shared__ __hip_bfloat16 Bt[BN][BK + 8];

    const int tid  = threadIdx.x;
    const int lane = tid & 63;
    const int wv   = tid >> 6;
    const int wm   = wv >> 1, wn = wv & 1;
    const int m0   = blockIdx.y * BM;
    const int n0   = blockIdx.x * BN;

    f32x4 acc[4][4];
    #pragma unroll
    for (int i = 0; i < 4; ++i)
        #pragma unroll
        for (int jj = 0; jj < 4; ++jj)
            acc[i][jj] = (f32x4){0.f, 0.f, 0.f, 0.f};

    const int srow = tid >> 3;           // 0..31
    const int scol = (tid & 7) * 8;      // 0..56
    const int l15  = lane & 15;
    const int l4   = lane >> 4;

    for (int kt = 0; kt < DIM / BK; ++kt) {
        const int k0 = kt * BK;
        #pragma unroll
        for (int rnd = 0; rnd < 4; ++rnd) {
            const int row = rnd * 32 + srow;
            *(u16x8*)&At[row][scol] =
                cvt8_bf16(&A[(size_t)(m0 + row) * DIM + k0 + scol]);
            *(u16x8*)&Bt[row][scol] =
                cvt8_bf16(&B[(size_t)(n0 + row) * DIM + k0 + scol]);
        }
        __syncthreads();
        #pragma unroll
        for (int ks = 0; ks < 2; ++ks) {
            bf16x8 av[4], bv[4];
            #pragma unroll
            for (int i = 0; i < 4; ++i) {
                av[i] = *(const bf16x8*)&At[wm * 64 + i * 16 + l15][ks * 32 + l4 * 8];
                bv[i] = *(const bf16x8*)&Bt[wn * 64 + i * 16 + l15][ks * 32 + l4 * 8];
            }
            #pragma unroll
            for (int i = 0; i < 4; ++i)
                #pragma unroll
                for (int jj = 0; jj < 4; ++jj)
                    acc[i][jj] = __builtin_amdgcn_mfma_f32_16x16x32_bf16(
                        av[i], bv[jj], acc[i][jj], 0, 0, 0);
        }
        __syncthreads();
    }

    const int rq = l4 * 4;
    #pragma unroll
    for (int i = 0; i < 4; ++i) {
        const int rbase = m0 + wm * 64 + i * 16 + rq;
        #pragma unroll
        for (int jj = 0; jj < 4; ++jj) {
            const int col = n0 + wn * 64 + jj * 16 + l15;
            #pragma unroll
            for (int r2 = 0; r2 < 4; ++r2)
                C[(size_t)(rbase + r2) * VOCAB + col] = acc[i][jj][r2];
        }
    }
}

// ---------------------------------------------------------------------------
extern "C" void kernel_launch(void* const* d_in, const int* in_sizes, int n_in,
                              void* d_out, int out_size, void* d_ws, size_t ws_size,
                              hipStream_t stream)
{
    (void)in_sizes; (void)n_in; (void)out_size; (void)ws_size;
    const int*   ids  = (const int*)  d_in[0];
    const float* embW = (const float*)d_in[1];
    const float* hst  = (const float*)d_in[2];
    const float* gW   = (const float*)d_in[3];
    const float* gB   = (const float*)d_in[4];
    const float* cW   = (const float*)d_in[5];
    const float* cB   = (const float*)d_in[6];
    const float* outW = (const float*)d_in[7];
    float* logits = (float*)d_out;

    // workspace carve-up (~17.4 MiB)
    char* ws = (char*)d_ws;
    unsigned* bar  = (unsigned*)ws;                               // 16 KiB
    float*    rbuf = (float*)(ws + 16384);                        // 128 KiB
    float*    hbuf = (float*)(ws + 16384 + 131072);               // 512 KiB
    float*    ysf  = (float*)(ws + 16384 + 131072 + 524288);      // 16 MiB

    // 1) zero slot arrays
    bar_init_kernel<<<dim3(1), dim3(1024), 0, stream>>>(bar);

    // 2) layer-pipelined persistent-weight GRU scan (fence-free sc1 comms)
    gru_scan<<<dim3(SCAN_BLOCKS), dim3(SCAN_THREADS), 0, stream>>>(
        ids, embW, hst, gW, gB, cW, cB, hbuf, rbuf, ysf, bar);

    // 3) logits GEMM
    out_gemm<<<dim3(VOCAB / BN, (NB * SEQ) / BM), dim3(256), 0, stream>>>(ysf, outW, logits);
}

// Round 11
// 9824.374 us; speedup vs baseline: 7.9440x; 1.3824x over previous
//
#include <hip/hip_runtime.h>
#include <hip/hip_bf16.h>

#define VOCAB  32000
#define DIM    1024
#define NLAYER 4
#define NB     8
#define SEQ    512

#define NGROUP       4
#define GBLKS        64                    // blocks per layer-group
#define SCAN_BLOCKS  (NGROUP * GBLKS)      // 256
#define SCAN_THREADS 512                   // 8 waves; wave owns 2 full rows

typedef __attribute__((ext_vector_type(8))) short          bf16x8;
typedef __attribute__((ext_vector_type(4))) float          f32x4;
typedef __attribute__((ext_vector_type(8))) unsigned short u16x8;
typedef __attribute__((ext_vector_type(2))) _Float16       h2f;
typedef __attribute__((ext_vector_type(4))) _Float16       h4f;
typedef __attribute__((ext_vector_type(8))) _Float16       h8f;

__device__ __forceinline__ u16x8 cvt8_bf16(const float* p) {
    float4 f0 = *(const float4*)p;
    float4 f1 = *(const float4*)(p + 4);
    union { __hip_bfloat16 h[8]; u16x8 v; } u;
    u.h[0] = __float2bfloat16(f0.x); u.h[1] = __float2bfloat16(f0.y);
    u.h[2] = __float2bfloat16(f0.z); u.h[3] = __float2bfloat16(f0.w);
    u.h[4] = __float2bfloat16(f1.x); u.h[5] = __float2bfloat16(f1.y);
    u.h[6] = __float2bfloat16(f1.z); u.h[7] = __float2bfloat16(f1.w);
    return u.v;
}

// ---- full-wave sum via DPP (VALU pipe only, no LDS ops). Result in lane 63.
//      Sequence = LLVM atomic-optimizer gfx9 pattern.
__device__ __forceinline__ float dppsum(float v) {
    int x;
    x = __builtin_amdgcn_update_dpp(0, __float_as_int(v), 0x111, 0xf, 0xf, true); v += __int_as_float(x); // row_shr:1
    x = __builtin_amdgcn_update_dpp(0, __float_as_int(v), 0x112, 0xf, 0xf, true); v += __int_as_float(x); // row_shr:2
    x = __builtin_amdgcn_update_dpp(0, __float_as_int(v), 0x114, 0xf, 0xf, true); v += __int_as_float(x); // row_shr:4
    x = __builtin_amdgcn_update_dpp(0, __float_as_int(v), 0x118, 0xf, 0xf, true); v += __int_as_float(x); // row_shr:8
    x = __builtin_amdgcn_update_dpp(0, __float_as_int(v), 0x142, 0xa, 0xf, true); v += __int_as_float(x); // row_bcast:15 -> rows 1,3
    x = __builtin_amdgcn_update_dpp(0, __float_as_int(v), 0x143, 0xc, 0xf, true); v += __int_as_float(x); // row_bcast:31 -> rows 2,3
    return v;
}

// ---- coherence-point (L3) loads/stores: bypass per-XCD L2 (no fences needed)
__device__ __forceinline__ void ld4v(f32x4& d, const float* p) {
    asm volatile("global_load_dwordx4 %0, %1, off sc0 sc1"
                 : "=&v"(d) : "v"(p));
}
__device__ __forceinline__ void st1v(float* p, float v) {
    asm volatile("global_store_dword %0, %1, off sc0 sc1"
                 :: "v"(p), "v"(v) : "memory");
}
__device__ __forceinline__ void vmwait0() {
    asm volatile("s_waitcnt vmcnt(0)" ::: "memory");
}

// ---------------------------------------------------------------------------
__global__ void bar_init_kernel(unsigned* __restrict__ bar) {
    bar[threadIdx.x]        = 0u;
    bar[threadIdx.x + 1024] = 0u;
    bar[threadIdx.x + 2048] = 0u;
    bar[threadIdx.x + 3072] = 0u;   // 4096 words = 16 KiB
}

// ---------------------------------------------------------------------------
// Fence-free slot barrier (proven round 10).
// ---------------------------------------------------------------------------
__device__ __forceinline__ void slot_bar(unsigned* __restrict__ slots, int bkg,
                                         unsigned seq, bool& dead) {
    __syncthreads();
    const int tid = threadIdx.x;
    if (tid == 0)
        __hip_atomic_store(&slots[bkg * 8], seq, __ATOMIC_RELAXED,
                           __HIP_MEMORY_SCOPE_AGENT);
    if (tid < 64 && !dead) {
        unsigned guard = 0;
        for (;;) {
            unsigned v = __hip_atomic_load(&slots[tid * 8], __ATOMIC_RELAXED,
                                           __HIP_MEMORY_SCOPE_AGENT);
            if (__all((int)(v >= seq))) break;
            __builtin_amdgcn_s_sleep(1);
            if (++guard > (1u << 16)) { dead = true; break; }
        }
    }
    __syncthreads();
}

// ---------------------------------------------------------------------------
// Layer-pipelined persistent-weight GRU scan; DPP reductions + interleaved
// x|h fp16 LDS layout (one ds_read_b128 feeds both dot inputs).
// ---------------------------------------------------------------------------
__global__ void __launch_bounds__(SCAN_THREADS)
__attribute__((amdgpu_waves_per_eu(2, 2)))
gru_scan(
    const int*   __restrict__ ids,     // [NB][SEQ]
    const float* __restrict__ embW,    // [VOCAB][DIM]
    const float* __restrict__ hstart,  // [NLAYER][DIM]
    const float* __restrict__ gW,      // [NLAYER][2*DIM][2*DIM]
    const float* __restrict__ gB,      // [NLAYER][2*DIM]
    const float* __restrict__ cW,      // [NLAYER][DIM][2*DIM]
    const float* __restrict__ cB,      // [NLAYER][DIM]
    float* __restrict__ hbuf,          // [4][NLAYER][NB][DIM]
    float* __restrict__ rbuf,          // [NGROUP][NB][DIM]
    float* __restrict__ ysf,           // [NB][SEQ][DIM] fp32
    unsigned* __restrict__ bar)
{
    // [b][k/4] = 16B: halves 0..3 = x fp16 (later rh), 4..7 = h_old fp16
    __shared__ h8f  lxh2[NB][256];      // 32KB
    __shared__ float zs[8][2][NB];
    __shared__ float cs[8][2][NB];

    const int tid  = threadIdx.x;
    const int lane = tid & 63;
    const int wv   = tid >> 6;               // 0..7
    const int g    = blockIdx.x >> 6;        // layer group 0..3
    const int bkg  = blockIdx.x & (GBLKS-1); // 0..63
    const int j0   = bkg * 16 + wv * 2;      // wave's first row

    // ---- persistent fp16 weights: [row][type z,r,c][16 h2] ----
    h2f W[2][3][16];
    float bzv[2], brv[2], cbv[2];
    #pragma unroll
    for (int rr = 0; rr < 2; ++rr) {
        const int j = j0 + rr;
        const float* wz = gW + ((size_t)g * 2048 + j) * 2048;
        const float* wr = gW + ((size_t)g * 2048 + 1024 + j) * 2048;
        const float* wc = cW + ((size_t)g * 1024 + j) * 2048;
        #pragma unroll
        for (int it = 0; it < 4; ++it) {
            const int k0 = it * 256 + lane * 4;
            float4 f;
            f = *(const float4*)(wz + k0);
            W[rr][0][2*it]     = h2f{(_Float16)f.x, (_Float16)f.y};
            W[rr][0][2*it+1]   = h2f{(_Float16)f.z, (_Float16)f.w};
            f = *(const float4*)(wz + 1024 + k0);
            W[rr][0][8+2*it]   = h2f{(_Float16)f.x, (_Float16)f.y};
            W[rr][0][9+2*it]   = h2f{(_Float16)f.z, (_Float16)f.w};
            f = *(const float4*)(wr + k0);
            W[rr][1][2*it]     = h2f{(_Float16)f.x, (_Float16)f.y};
            W[rr][1][2*it+1]   = h2f{(_Float16)f.z, (_Float16)f.w};
            f = *(const float4*)(wr + 1024 + k0);
            W[rr][1][8+2*it]   = h2f{(_Float16)f.x, (_Float16)f.y};
            W[rr][1][9+2*it]   = h2f{(_Float16)f.z, (_Float16)f.w};
            f = *(const float4*)(wc + k0);
            W[rr][2][2*it]     = h2f{(_Float16)f.x, (_Float16)f.y};
            W[rr][2][2*it+1]   = h2f{(_Float16)f.z, (_Float16)f.w};
            f = *(const float4*)(wc + 1024 + k0);
            W[rr][2][8+2*it]   = h2f{(_Float16)f.x, (_Float16)f.y};
            W[rr][2][9+2*it]   = h2f{(_Float16)f.z, (_Float16)f.w};
        }
        bzv[rr] = gB[g * 2048 + j];
        brv[rr] = gB[g * 2048 + 1024 + j];
        cbv[rr] = cB[g * DIM + j];
    }
    #pragma unroll
    for (int rr = 0; rr < 2; ++rr)
        #pragma unroll
        for (int ty = 0; ty < 3; ++ty)
            #pragma unroll
            for (int i = 0; i < 16; ++i)
                asm volatile("" : "+v"(W[rr][ty][i]));   // pin: no remat/spill

    bool dead = false;

    unsigned* slots1g = bar + g * 512;
    unsigned* slots2g = bar + 2048 + g * 512;
    unsigned* s2prev  = (g > 0)          ? bar + 2048 + (g - 1) * 512 : nullptr;
    unsigned* s1next  = (g < NGROUP - 1) ? bar + (g + 1) * 512        : nullptr;

    float* rbufg = rbuf + (size_t)g * NB * DIM;

    // lane-local copy of own rows' h(t-1): batch = lane (lanes 0..7)
    float hkeep[2] = { hstart[g * DIM + j0], hstart[g * DIM + j0 + 1] };

    // init own layer h(-1) into ring slot 3 (sc1 stores -> L3)
    if (tid < 128) {
        int e = bkg * 128 + tid;   // 0..8191
        st1v(&hbuf[((size_t)3 * NLAYER + g) * NB * DIM + e],
             hstart[g * DIM + (e & (DIM - 1))]);
    }
    slot_bar(slots2g, bkg, 1u, dead);

    for (int t = 0; t < SEQ; ++t) {
        const int so = (t + 3) & 3;   // h_old slot
        const int sw = t & 3;         // h_new slot
        const float* hsrc = hbuf + ((size_t)so * NLAYER + g) * NB * DIM;
        float*       hdst = hbuf + ((size_t)sw * NLAYER + g) * NB * DIM;

        // ---- peer gates (fence-free) ----
        {
            const unsigned need_a = (g > 0) ? (unsigned)(t + 2) : 0u;
            const unsigned need_b = (g < NGROUP - 1 && t >= 4) ? (unsigned)(t - 3) : 0u;
            if (tid < 64 && !dead && (need_a | need_b)) {
                unsigned guard = 0;
                for (;;) {
                    bool ok = true;
                    if (need_a)
                        ok &= (__hip_atomic_load(&s2prev[tid * 8], __ATOMIC_RELAXED,
                                                 __HIP_MEMORY_SCOPE_AGENT) >= need_a);
                    if (need_b)
                        ok &= (__hip_atomic_load(&s1next[tid * 8], __ATOMIC_RELAXED,
                                                 __HIP_MEMORY_SCOPE_AGENT) >= need_b);
                    if (__all((int)ok)) break;
                    __builtin_amdgcn_s_sleep(1);
                    if (++guard > (1u << 16)) { dead = true; break; }
                }
            }
            __syncthreads();
        }

        // ---- stage {xin|h_old} -> lxh2 (one b128 write per unit) ----
        {
            f32x4 xv[4], hv[4];
            if (g == 0) {
                #pragma unroll
                for (int q = 0; q < 4; ++q) {
                    int e = q * SCAN_THREADS + tid;
                    int row = ids[(e >> 8) * SEQ + t];
                    xv[q] = ((const f32x4*)(embW + (size_t)row * DIM))[e & 255];
                }
            } else {
                const float* src = hbuf + ((size_t)sw * NLAYER + (g - 1)) * NB * DIM;
                #pragma unroll
                for (int q = 0; q < 4; ++q)
                    ld4v(xv[q], src + (size_t)(q * SCAN_THREADS + tid) * 4);
            }
            #pragma unroll
            for (int q = 0; q < 4; ++q)
                ld4v(hv[q], hsrc + (size_t)(q * SCAN_THREADS + tid) * 4);
            vmwait0();
            asm volatile("" : "+v"(xv[0]), "+v"(xv[1]), "+v"(xv[2]), "+v"(xv[3]),
                             "+v"(hv[0]), "+v"(hv[1]), "+v"(hv[2]), "+v"(hv[3]));
            #pragma unroll
            for (int q = 0; q < 4; ++q) {
                int e = q * SCAN_THREADS + tid;
                h8f pk;
                pk[0] = (_Float16)xv[q][0]; pk[1] = (_Float16)xv[q][1];
                pk[2] = (_Float16)xv[q][2]; pk[3] = (_Float16)xv[q][3];
                pk[4] = (_Float16)hv[q][0]; pk[5] = (_Float16)hv[q][1];
                pk[6] = (_Float16)hv[q][2]; pk[7] = (_Float16)hv[q][3];
                lxh2[e >> 8][e & 255] = pk;
            }
        }
        __syncthreads();

        // ---- Phase A: full z, r, candA dots for 2 rows x 8 batches ----
        float az[2][NB], ar[2][NB], ac[2][NB];
        #pragma unroll
        for (int rr = 0; rr < 2; ++rr)
            #pragma unroll
            for (int b = 0; b < NB; ++b) { az[rr][b] = 0.f; ar[rr][b] = 0.f; ac[rr][b] = 0.f; }

        #pragma unroll
        for (int it = 0; it < 4; ++it) {
            const int k4 = it * 64 + lane;
            #pragma unroll
            for (int b = 0; b < NB; ++b) {
                h8f xh = lxh2[b][k4];
                h2f x01{xh[0], xh[1]}, x23{xh[2], xh[3]};
                h2f h01{xh[4], xh[5]}, h23{xh[6], xh[7]};
                #pragma unroll
                for (int rr = 0; rr < 2; ++rr) {
                    az[rr][b] = __builtin_amdgcn_fdot2(W[rr][0][2*it],   x01, az[rr][b], false);
                    az[rr][b] = __builtin_amdgcn_fdot2(W[rr][0][2*it+1], x23, az[rr][b], false);
                    az[rr][b] = __builtin_amdgcn_fdot2(W[rr][0][8+2*it], h01, az[rr][b], false);
                    az[rr][b] = __builtin_amdgcn_fdot2(W[rr][0][9+2*it], h23, az[rr][b], false);
                    ar[rr][b] = __builtin_amdgcn_fdot2(W[rr][1][2*it],   x01, ar[rr][b], false);
                    ar[rr][b] = __builtin_amdgcn_fdot2(W[rr][1][2*it+1], x23, ar[rr][b], false);
                    ar[rr][b] = __builtin_amdgcn_fdot2(W[rr][1][8+2*it], h01, ar[rr][b], false);
                    ar[rr][b] = __builtin_amdgcn_fdot2(W[rr][1][9+2*it], h23, ar[rr][b], false);
                    ac[rr][b] = __builtin_amdgcn_fdot2(W[rr][2][2*it],   x01, ac[rr][b], false);
                    ac[rr][b] = __builtin_amdgcn_fdot2(W[rr][2][2*it+1], x23, ac[rr][b], false);
                }
            }
        }
        #pragma unroll
        for (int rr = 0; rr < 2; ++rr)
            #pragma unroll
            for (int b = 0; b < NB; ++b) {
                az[rr][b] = dppsum(az[rr][b]);
                ar[rr][b] = dppsum(ar[rr][b]);
                ac[rr][b] = dppsum(ac[rr][b]);
            }

        if (lane == 63) {   // sums live in lane 63
            #pragma unroll
            for (int rr = 0; rr < 2; ++rr)
                #pragma unroll
                for (int b = 0; b < NB; ++b) {
                    zs[wv][rr][b] = 1.f / (1.f + expf(-(az[rr][b] + bzv[rr])));
                    cs[wv][rr][b] = ac[rr][b];
                    st1v(rbufg + b * DIM + j0 + rr,
                         1.f / (1.f + expf(-(ar[rr][b] + brv[rr]))));
                }
        }
        // bar1: r published / xin consumed
        slot_bar(slots1g, bkg, (unsigned)(t + 1), dead);

        // ---- stage rh = r * h_old into the x-half of lxh2 ----
        {
            f32x4 rv[4]; h4f hh[4];
            #pragma unroll
            for (int q = 0; q < 4; ++q) {
                int e = q * SCAN_THREADS + tid;
                hh[q] = *(const h4f*)((const _Float16*)&lxh2[e >> 8][e & 255] + 4);
                ld4v(rv[q], rbufg + (size_t)e * 4);
            }
            vmwait0();
            asm volatile("" : "+v"(rv[0]), "+v"(rv[1]), "+v"(rv[2]), "+v"(rv[3]));
            #pragma unroll
            for (int q = 0; q < 4; ++q) {
                int e = q * SCAN_THREADS + tid;
                h4f rh;
                rh[0] = (_Float16)(rv[q][0] * (float)hh[q][0]);
                rh[1] = (_Float16)(rv[q][1] * (float)hh[q][1]);
                rh[2] = (_Float16)(rv[q][2] * (float)hh[q][2]);
                rh[3] = (_Float16)(rv[q][3] * (float)hh[q][3]);
                *(h4f*)&lxh2[e >> 8][e & 255] = rh;
            }
        }
        __syncthreads();

        // ---- Phase B: candB + state update ----
        float ab[2][NB];
        #pragma unroll
        for (int rr = 0; rr < 2; ++rr)
            #pragma unroll
            for (int b = 0; b < NB; ++b) ab[rr][b] = 0.f;
        #pragma unroll
        for (int it = 0; it < 4; ++it) {
            const int k4 = it * 64 + lane;
            #pragma unroll
            for (int b = 0; b < NB; ++b) {
                h4f pv = *(const h4f*)&lxh2[b][k4];
                h2f p01{pv[0], pv[1]}, p23{pv[2], pv[3]};
                #pragma unroll
                for (int rr = 0; rr < 2; ++rr) {
                    ab[rr][b] = __builtin_amdgcn_fdot2(W[rr][2][8+2*it], p01, ab[rr][b], false);
                    ab[rr][b] = __builtin_amdgcn_fdot2(W[rr][2][9+2*it], p23, ab[rr][b], false);
                }
            }
        }
        #pragma unroll
        for (int rr = 0; rr < 2; ++rr)
            #pragma unroll
            for (int b = 0; b < NB; ++b) ab[rr][b] = dppsum(ab[rr][b]);

        if (lane == 63) {
            #pragma unroll
            for (int rr = 0; rr < 2; ++rr)
                #pragma unroll
                for (int b = 0; b < NB; ++b) cs[wv][rr][b] += ab[rr][b];
        }
        if (lane < NB) {   // same-wave LDS RAW after lane-63 writes
            const int b = lane;
            #pragma unroll
            for (int rr = 0; rr < 2; ++rr) {
                const int j = j0 + rr;
                const float cand = tanhf(cs[wv][rr][b] + cbv[rr]);
                const float z    = zs[wv][rr][b];
                const float hn   = z * hkeep[rr] + (1.f - z) * cand;
                hkeep[rr] = hn;
                st1v(hdst + b * DIM + j, hn);          // sc1 -> L3
                if (g == NGROUP - 1)
                    ysf[((size_t)b * SEQ + t) * DIM + j] = hn;
            }
        }
        // bar2: h(t) published
        slot_bar(slots2g, bkg, (unsigned)(t + 2), dead);
    }

    if (dead && tid == 0)
        ysf[blockIdx.x] = 1.0e8f;   // unmistakable failure sentinel
}

// ---------------------------------------------------------------------------
// Logits GEMM (unchanged): C[m][n] = sum_k ys[m][k] * outW[n][k]
// ---------------------------------------------------------------------------
#define BM 128
#define BN 128
#define BK 64

__global__ void __launch_bounds__(256) out_gemm(
    const float* __restrict__ A,   // [4096][1024]  fp32
    const float* __restrict__ B,   // [32000][1024] fp32
    float* __restrict__ C)         // [4096][32000]
{
    __shared__ __hip_bfloat16 At[BM][BK + 8];
    __shared__ __hip_bfloat16 Bt[BN][BK + 8];

    const int tid  = threadIdx.x;
    const int lane = tid & 63;
    const int wv   = tid >> 6;
    const int wm   = wv >> 1, wn = wv & 1;
    const int m0   = blockIdx.y * BM;
    const int n0   = blockIdx.x * BN;

    f32x4 acc[4][4];
    #pragma unroll
    for (int i = 0; i < 4; ++i)
        #pragma unroll
        for (int jj = 0; jj < 4; ++jj)
            acc[i][jj] = (f32x4){0.f, 0.f, 0.f, 0.f};

    const int srow = tid >> 3;           // 0..31
    const int scol = (tid & 7) * 8;      // 0..56
    const int l15  = lane & 15;
    const int l4   = lane >> 4;

    for (int kt = 0; kt < DIM / BK; ++kt) {
        const int k0 = kt * BK;
        #pragma unroll
        for (int rnd = 0; rnd < 4; ++rnd) {
            const int row = rnd * 32 + srow;
            *(u16x8*)&At[row][scol] =
                cvt8_bf16(&A[(size_t)(m0 + row) * DIM + k0 + scol]);
            *(u16x8*)&Bt[row][scol] =
                cvt8_bf16(&B[(size_t)(n0 + row) * DIM + k0 + scol]);
        }
        __syncthreads();
        #pragma unroll
        for (int ks = 0; ks < 2; ++ks) {
            bf16x8 av[4], bv[4];
            #pragma unroll
            for (int i = 0; i < 4; ++i) {
                av[i] = *(const bf16x8*)&At[wm * 64 + i * 16 + l15][ks * 32 + l4 * 8];
                bv[i] = *(const bf16x8*)&Bt[wn * 64 + i * 16 + l15][ks * 32 + l4 * 8];
            }
            #pragma unroll
            for (int i = 0; i < 4; ++i)
                #pragma unroll
                for (int jj = 0; jj < 4; ++jj)
                    acc[i][jj] = __builtin_amdgcn_mfma_f32_16x16x32_bf16(
                        av[i], bv[jj], acc[i][jj], 0, 0, 0);
        }
        __syncthreads();
    }

    const int rq = l4 * 4;
    #pragma unroll
    for (int i = 0; i < 4; ++i) {
        const int rbase = m0 + wm * 64 + i * 16 + rq;
        #pragma unroll
        for (int jj = 0; jj < 4; ++jj) {
            const int col = n0 + wn * 64 + jj * 16 + l15;
            #pragma unroll
            for (int r2 = 0; r2 < 4; ++r2)
                C[(size_t)(rbase + r2) * VOCAB + col] = acc[i][jj][r2];
        }
    }
}

// ---------------------------------------------------------------------------
extern "C" void kernel_launch(void* const* d_in, const int* in_sizes, int n_in,
                              void* d_out, int out_size, void* d_ws, size_t ws_size,
                              hipStream_t stream)
{
    (void)in_sizes; (void)n_in; (void)out_size; (void)ws_size;
    const int*   ids  = (const int*)  d_in[0];
    const float* embW = (const float*)d_in[1];
    const float* hst  = (const float*)d_in[2];
    const float* gW   = (const float*)d_in[3];
    const float* gB   = (const float*)d_in[4];
    const float* cW   = (const float*)d_in[5];
    const float* cB   = (const float*)d_in[6];
    const float* outW = (const float*)d_in[7];
    float* logits = (float*)d_out;

    // workspace carve-up (~17.4 MiB)
    char* ws = (char*)d_ws;
    unsigned* bar  = (unsigned*)ws;                               // 16 KiB
    float*    rbuf = (float*)(ws + 16384);                        // 128 KiB
    float*    hbuf = (float*)(ws + 16384 + 131072);               // 512 KiB
    float*    ysf  = (float*)(ws + 16384 + 131072 + 524288);      // 16 MiB

    // 1) zero slot arrays
    bar_init_kernel<<<dim3(1), dim3(1024), 0, stream>>>(bar);

    // 2) layer-pipelined persistent-weight GRU scan (DPP reduce, packed LDS)
    gru_scan<<<dim3(SCAN_BLOCKS), dim3(SCAN_THREADS), 0, stream>>>(
        ids, embW, hst, gW, gB, cW, cB, hbuf, rbuf, ysf, bar);

    // 3) logits GEMM
    out_gemm<<<dim3(VOCAB / BN, (NB * SEQ) / BM), dim3(256), 0, stream>>>(ysf, outW, logits);
}

// Round 12
// 4163.247 us; speedup vs baseline: 18.7461x; 2.3598x over previous
//
#include <hip/hip_runtime.h>
#include <hip/hip_bf16.h>

#define VOCAB  32000
#define DIM    1024
#define NLAYER 4
#define NB     8
#define SEQ    512

#define NGROUP       4
#define GBLKS        64                    // blocks per layer-group
#define SCAN_BLOCKS  (NGROUP * GBLKS)      // 256
#define SCAN_THREADS 512                   // 8 waves, role-split
#define ROWH         2056                  // act row stride (2048 + 8 pad halves)

typedef __attribute__((ext_vector_type(8))) short          bf16x8;
typedef __attribute__((ext_vector_type(4))) float          f32x4;
typedef __attribute__((ext_vector_type(8))) unsigned short u16x8;
typedef __attribute__((ext_vector_type(8))) _Float16       h8f;

__device__ __forceinline__ u16x8 cvt8_bf16(const float* p) {
    float4 f0 = *(const float4*)p;
    float4 f1 = *(const float4*)(p + 4);
    union { __hip_bfloat16 h[8]; u16x8 v; } u;
    u.h[0] = __float2bfloat16(f0.x); u.h[1] = __float2bfloat16(f0.y);
    u.h[2] = __float2bfloat16(f0.z); u.h[3] = __float2bfloat16(f0.w);
    u.h[4] = __float2bfloat16(f1.x); u.h[5] = __float2bfloat16(f1.y);
    u.h[6] = __float2bfloat16(f1.z); u.h[7] = __float2bfloat16(f1.w);
    return u.v;
}

__device__ __forceinline__ h8f pack8(f32x4 a, f32x4 b) {
    h8f o;
    o[0] = (_Float16)a[0]; o[1] = (_Float16)a[1];
    o[2] = (_Float16)a[2]; o[3] = (_Float16)a[3];
    o[4] = (_Float16)b[0]; o[5] = (_Float16)b[1];
    o[6] = (_Float16)b[2]; o[7] = (_Float16)b[3];
    return o;
}

// ---- coherence-point (L3) loads/stores: bypass per-XCD L2 (no fences needed)
__device__ __forceinline__ void ld4v(f32x4& d, const float* p) {
    asm volatile("global_load_dwordx4 %0, %1, off sc0 sc1"
                 : "=&v"(d) : "v"(p));
}
__device__ __forceinline__ void st1v(float* p, float v) {
    asm volatile("global_store_dword %0, %1, off sc0 sc1"
                 :: "v"(p), "v"(v) : "memory");
}
__device__ __forceinline__ void vmwait0() {
    asm volatile("s_waitcnt vmcnt(0)" ::: "memory");
}

// ---------------------------------------------------------------------------
__global__ void bar_init_kernel(unsigned* __restrict__ bar) {
    bar[threadIdx.x]        = 0u;
    bar[threadIdx.x + 1024] = 0u;
    bar[threadIdx.x + 2048] = 0u;
    bar[threadIdx.x + 3072] = 0u;   // 4096 words
}

// ---------------------------------------------------------------------------
// Fence-free slot barrier (proven rounds 10-11).
// ---------------------------------------------------------------------------
__device__ __forceinline__ void slot_bar(unsigned* __restrict__ slots, int bkg,
                                         unsigned seq, bool& dead) {
    __syncthreads();
    const int tid = threadIdx.x;
    if (tid == 0)
        __hip_atomic_store(&slots[bkg * 8], seq, __ATOMIC_RELAXED,
                           __HIP_MEMORY_SCOPE_AGENT);
    if (tid < 64 && !dead) {
        unsigned guard = 0;
        for (;;) {
            unsigned v = __hip_atomic_load(&slots[tid * 8], __ATOMIC_RELAXED,
                                           __HIP_MEMORY_SCOPE_AGENT);
            if (__all((int)(v >= seq))) break;
            __builtin_amdgcn_s_sleep(1);
            if (++guard > (1u << 16)) { dead = true; break; }
        }
    }
    __syncthreads();
}

// ---------------------------------------------------------------------------
// MFMA layer-pipelined persistent-weight GRU scan.
// Block owns 16 rows (j = bkg*16..+16) of its group's layer. Wave roles:
//  w0-3: z+r MFMA over K-quarter [wv*512, +512)   (A-frags: 128 pinned VGPR)
//  w4-5: candA K-half (phase A) / candB K-half over rh (phase B)
//  w6:   z-combine + tanh + state update (hold[] in regs)
//  w7:   r-combine -> sigmoid -> rbuf (sc1)
// act[b][0..1024) = x (later rh), [1024..2048) = h_old, fp16, pad 8 halves.
// MFMA 16x16x32 f16: A row=lane&15 (global row j), k=(lane>>4)*8+i;
// B from act[col&7][k] (16B contiguous/lane); D col=lane&15, row=(lane>>4)*4+reg.
// ---------------------------------------------------------------------------
__global__ void __launch_bounds__(SCAN_THREADS)
__attribute__((amdgpu_waves_per_eu(2, 2)))
gru_scan(
    const int*   __restrict__ ids,     // [NB][SEQ]
    const float* __restrict__ embW,    // [VOCAB][DIM]
    const float* __restrict__ hstart,  // [NLAYER][DIM]
    const float* __restrict__ gW,      // [NLAYER][2*DIM][2*DIM]
    const float* __restrict__ gB,      // [NLAYER][2*DIM]
    const float* __restrict__ cW,      // [NLAYER][DIM][2*DIM]
    const float* __restrict__ cB,      // [NLAYER][DIM]
    float* __restrict__ hbuf,          // [4][NLAYER][NB][DIM]
    float* __restrict__ rbuf,          // [NGROUP][NB][DIM]
    float* __restrict__ ysf,           // [NB][SEQ][DIM] fp32
    unsigned* __restrict__ bar)
{
    __shared__ _Float16 act[NB][ROWH];      // 32,896 B
    __shared__ float pz[4][4][64];          // z partials  [wv][reg][lane]
    __shared__ float pr[4][4][64];          // r partials
    __shared__ float pc[2][4][64];          // candA partials
    __shared__ float pcb[2][4][64];         // candB partials

    const int tid   = threadIdx.x;
    const int lane  = tid & 63;
    const int wv    = tid >> 6;               // 0..7
    const int l15   = lane & 15;
    const int lgq   = lane >> 4;              // 0..3
    const int bcol  = l15 & 7;                // batch (cols 8..15 dup 0..7)
    const int g     = blockIdx.x >> 6;        // layer group
    const int bkg   = blockIdx.x & (GBLKS-1);
    const int jbase = bkg * 16;
    const int jrow  = jbase + l15;            // this lane's A row

    // ---- persistent A-fragment weights (pinned) ----
    h8f Wa[16], Wb[16];
    if (wv < 4) {                // z (Wa) + r (Wb), K-quarter
        const int kb = wv * 512;
        const float* wzp = gW + ((size_t)g * 2048 + jrow) * 2048;
        const float* wrp = gW + ((size_t)g * 2048 + 1024 + jrow) * 2048;
        #pragma unroll
        for (int kc = 0; kc < 16; ++kc) {
            const int k0 = kb + kc * 32 + lgq * 8;
            Wa[kc] = pack8(*(const f32x4*)(wzp + k0), *(const f32x4*)(wzp + k0 + 4));
            Wb[kc] = pack8(*(const f32x4*)(wrp + k0), *(const f32x4*)(wrp + k0 + 4));
        }
        #pragma unroll
        for (int kc = 0; kc < 16; ++kc) {
            asm volatile("" : "+v"(Wa[kc]));
            asm volatile("" : "+v"(Wb[kc]));
        }
    } else if (wv < 6) {         // candA (Wa, x-half) + candB (Wb, rh-half)
        const int kb = (wv - 4) * 512;
        const float* wcp = cW + ((size_t)g * 1024 + jrow) * 2048;
        #pragma unroll
        for (int kc = 0; kc < 16; ++kc) {
            const int k0 = kb + kc * 32 + lgq * 8;
            Wa[kc] = pack8(*(const f32x4*)(wcp + k0), *(const f32x4*)(wcp + k0 + 4));
            Wb[kc] = pack8(*(const f32x4*)(wcp + 1024 + k0), *(const f32x4*)(wcp + 1024 + k0 + 4));
        }
        #pragma unroll
        for (int kc = 0; kc < 16; ++kc) {
            asm volatile("" : "+v"(Wa[kc]));
            asm volatile("" : "+v"(Wb[kc]));
        }
    }

    float bz4[4], br4[4], cb4[4], hold[4], zreg[4];
    if (wv == 6) {
        #pragma unroll
        for (int r = 0; r < 4; ++r) {
            const int j = jbase + lgq * 4 + r;
            bz4[r]  = gB[g * 2048 + j];
            cb4[r]  = cB[g * 1024 + j];
            hold[r] = hstart[g * 1024 + j];
        }
    }
    if (wv == 7) {
        #pragma unroll
        for (int r = 0; r < 4; ++r)
            br4[r] = gB[g * 2048 + 1024 + jbase + lgq * 4 + r];
    }

    bool dead = false;
    unsigned* slots1g = bar + g * 512;
    unsigned* slots2g = bar + 2048 + g * 512;
    unsigned* s2prev  = (g > 0)          ? bar + 2048 + (g - 1) * 512 : nullptr;
    unsigned* s1next  = (g < NGROUP - 1) ? bar + (g + 1) * 512        : nullptr;
    float* rbufg = rbuf + (size_t)g * NB * DIM;

    // init own layer h(-1) into ring slot 3
    if (tid < 128) {
        int e = bkg * 128 + tid;
        st1v(&hbuf[((size_t)3 * NLAYER + g) * NB * DIM + e],
             hstart[g * DIM + (e & (DIM - 1))]);
    }
    slot_bar(slots2g, bkg, 1u, dead);

    for (int t = 0; t < SEQ; ++t) {
        const int so = (t + 3) & 3;
        const int sw = t & 3;
        const float* hsrc = hbuf + ((size_t)so * NLAYER + g) * NB * DIM;
        float*       hdst = hbuf + ((size_t)sw * NLAYER + g) * NB * DIM;

        // ---- peer gates (fence-free) ----
        {
            const unsigned need_a = (g > 0) ? (unsigned)(t + 2) : 0u;
            const unsigned need_b = (g < NGROUP - 1 && t >= 4) ? (unsigned)(t - 3) : 0u;
            if (tid < 64 && !dead && (need_a | need_b)) {
                unsigned guard = 0;
                for (;;) {
                    bool ok = true;
                    if (need_a)
                        ok &= (__hip_atomic_load(&s2prev[tid * 8], __ATOMIC_RELAXED,
                                                 __HIP_MEMORY_SCOPE_AGENT) >= need_a);
                    if (need_b)
                        ok &= (__hip_atomic_load(&s1next[tid * 8], __ATOMIC_RELAXED,
                                                 __HIP_MEMORY_SCOPE_AGENT) >= need_b);
                    if (__all((int)ok)) break;
                    __builtin_amdgcn_s_sleep(1);
                    if (++guard > (1u << 16)) { dead = true; break; }
                }
            }
            __syncthreads();
        }

        // ---- stage x -> act[.][0:1024), h_old -> act[.][1024:2048) fp16 ----
        {
            const int ub = tid & 127;        // 0..127 (8-half unit)
            const int b0 = tid >> 7;         // 0..3 (also stages b0+4)
            f32x4 xv0, xv1, xv2, xv3, hv0, hv1, hv2, hv3;
            if (g == 0) {
                const float* s0 = embW + (size_t)ids[b0 * SEQ + t] * DIM + ub * 8;
                const float* s1 = embW + (size_t)ids[(b0 + 4) * SEQ + t] * DIM + ub * 8;
                xv0 = *(const f32x4*)s0; xv1 = *(const f32x4*)(s0 + 4);
                xv2 = *(const f32x4*)s1; xv3 = *(const f32x4*)(s1 + 4);
            } else {
                const float* src = hbuf + ((size_t)sw * NLAYER + (g - 1)) * NB * DIM;
                ld4v(xv0, src + b0 * DIM + ub * 8);
                ld4v(xv1, src + b0 * DIM + ub * 8 + 4);
                ld4v(xv2, src + (b0 + 4) * DIM + ub * 8);
                ld4v(xv3, src + (b0 + 4) * DIM + ub * 8 + 4);
            }
            ld4v(hv0, hsrc + b0 * DIM + ub * 8);
            ld4v(hv1, hsrc + b0 * DIM + ub * 8 + 4);
            ld4v(hv2, hsrc + (b0 + 4) * DIM + ub * 8);
            ld4v(hv3, hsrc + (b0 + 4) * DIM + ub * 8 + 4);
            vmwait0();
            asm volatile("" : "+v"(xv0), "+v"(xv1), "+v"(xv2), "+v"(xv3),
                             "+v"(hv0), "+v"(hv1), "+v"(hv2), "+v"(hv3));
            *(h8f*)&act[b0][ub * 8]            = pack8(xv0, xv1);
            *(h8f*)&act[b0 + 4][ub * 8]        = pack8(xv2, xv3);
            *(h8f*)&act[b0][1024 + ub * 8]     = pack8(hv0, hv1);
            *(h8f*)&act[b0 + 4][1024 + ub * 8] = pack8(hv2, hv3);
        }
        __syncthreads();

        // ---- Phase A: MFMA dots ----
        if (wv < 6) {
            const int kb2 = (wv < 4) ? wv * 512 : (wv - 4) * 512;
            f32x4 accA = {0.f, 0.f, 0.f, 0.f};
            f32x4 accB = {0.f, 0.f, 0.f, 0.f};
            #pragma unroll
            for (int kc = 0; kc < 16; ++kc) {
                const h8f bf = *(const h8f*)&act[bcol][kb2 + kc * 32 + lgq * 8];
                accA = __builtin_amdgcn_mfma_f32_16x16x32_f16(Wa[kc], bf, accA, 0, 0, 0);
                if (wv < 4)
                    accB = __builtin_amdgcn_mfma_f32_16x16x32_f16(Wb[kc], bf, accB, 0, 0, 0);
            }
            if (wv < 4) {
                #pragma unroll
                for (int r = 0; r < 4; ++r) {
                    pz[wv][r][lane] = accA[r];
                    pr[wv][r][lane] = accB[r];
                }
            } else {
                #pragma unroll
                for (int r = 0; r < 4; ++r) pc[wv - 4][r][lane] = accA[r];
            }
        }
        __syncthreads();

        // ---- combine: z (w6, kept in regs) and r (w7 -> rbuf sc1) ----
        if (wv == 6) {
            #pragma unroll
            for (int r = 0; r < 4; ++r) {
                const float s = pz[0][r][lane] + pz[1][r][lane]
                              + pz[2][r][lane] + pz[3][r][lane] + bz4[r];
                zreg[r] = 1.f / (1.f + expf(-s));
            }
        }
        if (wv == 7) {
            #pragma unroll
            for (int r = 0; r < 4; ++r) {
                const float s = pr[0][r][lane] + pr[1][r][lane]
                              + pr[2][r][lane] + pr[3][r][lane] + br4[r];
                const float rg = 1.f / (1.f + expf(-s));
                if (l15 < 8)
                    st1v(rbufg + bcol * DIM + jbase + lgq * 4 + r, rg);
            }
        }
        // bar1: r published / xin consumed
        slot_bar(slots1g, bkg, (unsigned)(t + 1), dead);

        // ---- stage rh = r * h_old into act x-half ----
        {
            const int ub = tid & 127;
            const int b0 = tid >> 7;
            f32x4 rv0, rv1, rv2, rv3;
            ld4v(rv0, rbufg + b0 * DIM + ub * 8);
            ld4v(rv1, rbufg + b0 * DIM + ub * 8 + 4);
            ld4v(rv2, rbufg + (b0 + 4) * DIM + ub * 8);
            ld4v(rv3, rbufg + (b0 + 4) * DIM + ub * 8 + 4);
            h8f hh0 = *(const h8f*)&act[b0][1024 + ub * 8];
            h8f hh1 = *(const h8f*)&act[b0 + 4][1024 + ub * 8];
            vmwait0();
            asm volatile("" : "+v"(rv0), "+v"(rv1), "+v"(rv2), "+v"(rv3));
            h8f o0, o1;
            #pragma unroll
            for (int i = 0; i < 4; ++i) {
                o0[i]     = (_Float16)((float)hh0[i]     * rv0[i]);
                o0[i + 4] = (_Float16)((float)hh0[i + 4] * rv1[i]);
                o1[i]     = (_Float16)((float)hh1[i]     * rv2[i]);
                o1[i + 4] = (_Float16)((float)hh1[i + 4] * rv3[i]);
            }
            *(h8f*)&act[b0][ub * 8]     = o0;
            *(h8f*)&act[b0 + 4][ub * 8] = o1;
        }
        __syncthreads();

        // ---- Phase B: candB MFMA over rh ----
        if (wv == 4 || wv == 5) {
            const int kb2 = (wv - 4) * 512;
            f32x4 acc = {0.f, 0.f, 0.f, 0.f};
            #pragma unroll
            for (int kc = 0; kc < 16; ++kc) {
                const h8f bf = *(const h8f*)&act[bcol][kb2 + kc * 32 + lgq * 8];
                acc = __builtin_amdgcn_mfma_f32_16x16x32_f16(Wb[kc], bf, acc, 0, 0, 0);
            }
            #pragma unroll
            for (int r = 0; r < 4; ++r) pcb[wv - 4][r][lane] = acc[r];
        }
        __syncthreads();

        // ---- update (w6): cand = tanh(cA+cB+b), h = z*h + (1-z)*cand ----
        if (wv == 6) {
            #pragma unroll
            for (int r = 0; r < 4; ++r) {
                const float cand = tanhf(pc[0][r][lane] + pc[1][r][lane]
                                         + pcb[0][r][lane] + pcb[1][r][lane] + cb4[r]);
                const float hn = zreg[r] * hold[r] + (1.f - zreg[r]) * cand;
                hold[r] = hn;
                if (l15 < 8) {
                    const int j = jbase + lgq * 4 + r;
                    st1v(hdst + bcol * DIM + j, hn);
                    if (g == NGROUP - 1)
                        ysf[((size_t)bcol * SEQ + t) * DIM + j] = hn;
                }
            }
        }
        // bar2: h(t) published
        slot_bar(slots2g, bkg, (unsigned)(t + 2), dead);
    }

    if (dead && tid == 0)
        ysf[blockIdx.x] = 1.0e8f;   // unmistakable failure sentinel
}

// ---------------------------------------------------------------------------
// Logits GEMM (unchanged): C[m][n] = sum_k ys[m][k] * outW[n][k]
// ---------------------------------------------------------------------------
#define BM 128
#define BN 128
#define BK 64

__global__ void __launch_bounds__(256) out_gemm(
    const float* __restrict__ A,   // [4096][1024]  fp32
    const float* __restrict__ B,   // [32000][1024] fp32
    float* __restrict__ C)         // [4096][32000]
{
    __shared__ __hip_bfloat16 At[BM][BK + 8];
    __shared__ __hip_bfloat16 Bt[BN][BK + 8];

    const int tid  = threadIdx.x;
    const int lane = tid & 63;
    const int wv   = tid >> 6;
    const int wm   = wv >> 1, wn = wv & 1;
    const int m0   = blockIdx.y * BM;
    const int n0   = blockIdx.x * BN;

    f32x4 acc[4][4];
    #pragma unroll
    for (int i = 0; i < 4; ++i)
        #pragma unroll
        for (int jj = 0; jj < 4; ++jj)
            acc[i][jj] = (f32x4){0.f, 0.f, 0.f, 0.f};

    const int srow = tid >> 3;           // 0..31
    const int scol = (tid & 7) * 8;      // 0..56
    const int l15  = lane & 15;
    const int l4   = lane >> 4;

    for (int kt = 0; kt < DIM / BK; ++kt) {
        const int k0 = kt * BK;
        #pragma unroll
        for (int rnd = 0; rnd < 4; ++rnd) {
            const int row = rnd * 32 + srow;
            *(u16x8*)&At[row][scol] =
                cvt8_bf16(&A[(size_t)(m0 + row) * DIM + k0 + scol]);
            *(u16x8*)&Bt[row][scol] =
                cvt8_bf16(&B[(size_t)(n0 + row) * DIM + k0 + scol]);
        }
        __syncthreads();
        #pragma unroll
        for (int ks = 0; ks < 2; ++ks) {
            bf16x8 av[4], bv[4];
            #pragma unroll
            for (int i = 0; i < 4; ++i) {
                av[i] = *(const bf16x8*)&At[wm * 64 + i * 16 + l15][ks * 32 + l4 * 8];
                bv[i] = *(const bf16x8*)&Bt[wn * 64 + i * 16 + l15][ks * 32 + l4 * 8];
            }
            #pragma unroll
            for (int i = 0; i < 4; ++i)
                #pragma unroll
                for (int jj = 0; jj < 4; ++jj)
                    acc[i][jj] = __builtin_amdgcn_mfma_f32_16x16x32_bf16(
                        av[i], bv[jj], acc[i][jj], 0, 0, 0);
        }
        __syncthreads();
    }

    const int rq = l4 * 4;
    #pragma unroll
    for (int i = 0; i < 4; ++i) {
        const int rbase = m0 + wm * 64 + i * 16 + rq;
        #pragma unroll
        for (int jj = 0; jj < 4; ++jj) {
            const int col = n0 + wn * 64 + jj * 16 + l15;
            #pragma unroll
            for (int r2 = 0; r2 < 4; ++r2)
                C[(size_t)(rbase + r2) * VOCAB + col] = acc[i][jj][r2];
        }
    }
}

// ---------------------------------------------------------------------------
extern "C" void kernel_launch(void* const* d_in, const int* in_sizes, int n_in,
                              void* d_out, int out_size, void* d_ws, size_t ws_size,
                              hipStream_t stream)
{
    (void)in_sizes; (void)n_in; (void)out_size; (void)ws_size;
    const int*   ids  = (const int*)  d_in[0];
    const float* embW = (const float*)d_in[1];
    const float* hst  = (const float*)d_in[2];
    const float* gW   = (const float*)d_in[3];
    const float* gB   = (const float*)d_in[4];
    const float* cW   = (const float*)d_in[5];
    const float* cB   = (const float*)d_in[6];
    const float* outW = (const float*)d_in[7];
    float* logits = (float*)d_out;

    // workspace carve-up (~17.4 MiB)
    char* ws = (char*)d_ws;
    unsigned* bar  = (unsigned*)ws;                               // 16 KiB
    float*    rbuf = (float*)(ws + 16384);                        // 128 KiB
    float*    hbuf = (float*)(ws + 16384 + 131072);               // 512 KiB
    float*    ysf  = (float*)(ws + 16384 + 131072 + 524288);      // 16 MiB

    // 1) zero slot arrays
    bar_init_kernel<<<dim3(1), dim3(1024), 0, stream>>>(bar);

    // 2) MFMA layer-pipelined persistent-weight GRU scan
    gru_scan<<<dim3(SCAN_BLOCKS), dim3(SCAN_THREADS), 0, stream>>>(
        ids, embW, hst, gW, gB, cW, cB, hbuf, rbuf, ysf, bar);

    // 3) logits GEMM
    out_gemm<<<dim3(VOCAB / BN, (NB * SEQ) / BM), dim3(256), 0, stream>>>(ysf, outW, logits);
}